// Round 1
// baseline (4245.038 us; speedup 1.0000x reference)
//
#include <hip/hip_runtime.h>

#define N_NODES 100000
#define N_EDGES 1600000
#define D 128
#define TILE_ROWS 32

// ---------------- small utility kernels ----------------

__global__ void k_zero(float* __restrict__ p, int n) {
    int i = blockIdx.x * blockDim.x + threadIdx.x;
    if (i < n) p[i] = 0.0f;
}

__global__ void k_deg(const int* __restrict__ dst, const float* __restrict__ ew,
                      float* __restrict__ deg) {
    int i = blockIdx.x * blockDim.x + threadIdx.x;
    if (i < N_EDGES) atomicAdd(&deg[dst[i]], ew[i]);
}

__global__ void k_dis(float* __restrict__ deg) {
    int i = blockIdx.x * blockDim.x + threadIdx.x;
    if (i < N_NODES) deg[i] = rsqrtf(deg[i] + 1.0f);  // deg includes self-loop weight 1
}

// ---------------- GEMM: h = x @ W ; agg_init = dis^2 * h + b ----------------
// One block = 32 rows x 128 cols. W (64KB) + X tile (16KB) in LDS.
// NOTE: x and agg may alias (both = d_out). Safe because the block stages all
// of its 32 x-rows into LDS (then __syncthreads) before writing agg for those
// same rows, and blocks own disjoint row ranges.
__global__ __launch_bounds__(256) void k_gemm_agginit(
    const float* x, const float* __restrict__ W, const float* __restrict__ b,
    const float* __restrict__ dis, float* __restrict__ h, float* agg)
{
    __shared__ float Wl[D * D];          // 64 KB
    __shared__ float Xl[TILE_ROWS * D];  // 16 KB

    const int tx = threadIdx.x;
    const int row0 = blockIdx.x * TILE_ROWS;

    // stage W: 16384 floats = 4096 float4, 256 threads -> 16 each
    for (int i = tx; i < (D * D) / 4; i += 256)
        ((float4*)Wl)[i] = ((const float4*)W)[i];
    // stage X tile: 4096 floats = 1024 float4
    const float4* xsrc = (const float4*)(x + (size_t)row0 * D);
    for (int i = tx; i < (TILE_ROWS * D) / 4; i += 256)
        ((float4*)Xl)[i] = xsrc[i];
    __syncthreads();

    const int cg = (tx & 31) * 4;   // column group: 0..124
    const int rg = (tx >> 5) * 4;   // row group within tile: 0..28

    float acc[4][4] = {};
#pragma unroll 4
    for (int k = 0; k < D; ++k) {
        float4 w = *(const float4*)&Wl[k * D + cg];
#pragma unroll
        for (int ri = 0; ri < 4; ++ri) {
            float xv = Xl[(rg + ri) * D + k];
            acc[ri][0] += xv * w.x;
            acc[ri][1] += xv * w.y;
            acc[ri][2] += xv * w.z;
            acc[ri][3] += xv * w.w;
        }
    }

    float4 bv = *(const float4*)&b[cg];
#pragma unroll
    for (int ri = 0; ri < 4; ++ri) {
        int r = row0 + rg + ri;
        float di = dis[r];
        float d2 = di * di;
        float4 hv = make_float4(acc[ri][0], acc[ri][1], acc[ri][2], acc[ri][3]);
        *(float4*)&h[(size_t)r * D + cg] = hv;
        float4 av = make_float4(d2 * hv.x + bv.x, d2 * hv.y + bv.y,
                                d2 * hv.z + bv.z, d2 * hv.w + bv.w);
        *(float4*)&agg[(size_t)r * D + cg] = av;
    }
}

// ---------------- edge aggregation: agg[dst] += dis[src]*ew*dis[dst] * h[src] ----------------
// 64 lanes per edge, 2 floats per lane (float2 coalesced read of h row).
__global__ __launch_bounds__(256) void k_edge(
    const int* __restrict__ src, const int* __restrict__ dst,
    const float* __restrict__ ew, const float* __restrict__ dis,
    const float* __restrict__ h, float* __restrict__ agg)
{
    long long t = (long long)blockIdx.x * 256 + threadIdx.x;
    int e = (int)(t >> 6);
    int d = ((int)t & 63) * 2;
    if (e >= N_EDGES) return;
    int s = src[e], tn = dst[e];
    float coef = dis[s] * ew[e] * dis[tn];
    float2 hv = *(const float2*)&h[(size_t)s * D + d];
    atomicAdd(&agg[(size_t)tn * D + d], coef * hv.x);
    atomicAdd(&agg[(size_t)tn * D + d + 1], coef * hv.y);
}

// ---------------- PReLU in-place ----------------
__global__ void k_prelu(float* __restrict__ v, const float* __restrict__ a) {
    int i = blockIdx.x * blockDim.x + threadIdx.x;  // over N*32 float4s
    if (i >= N_NODES * (D / 4)) return;
    int c = (i & 31) * 4;
    float4 av = *(const float4*)&a[c];
    float4 x = ((float4*)v)[i];
    x.x = x.x >= 0.0f ? x.x : av.x * x.x;
    x.y = x.y >= 0.0f ? x.y : av.y * x.y;
    x.z = x.z >= 0.0f ? x.z : av.z * x.z;
    x.w = x.w >= 0.0f ? x.w : av.w * x.w;
    ((float4*)v)[i] = x;
}

// ---------------- launch ----------------

extern "C" void kernel_launch(void* const* d_in, const int* in_sizes, int n_in,
                              void* d_out, int out_size, void* d_ws, size_t ws_size,
                              hipStream_t stream) {
    const float* x   = (const float*)d_in[0];
    const int*   ei  = (const int*)d_in[1];          // [2, E] flattened
    const float* ew  = (const float*)d_in[2];
    const float* W1  = (const float*)d_in[3];
    const float* b1  = (const float*)d_in[4];
    const float* a1  = (const float*)d_in[5];
    const float* W2  = (const float*)d_in[6];
    const float* b2  = (const float*)d_in[7];
    const float* a2  = (const float*)d_in[8];
    const float* W3  = (const float*)d_in[9];
    const float* b3  = (const float*)d_in[10];
    const float* a3  = (const float*)d_in[11];

    const int* src = ei;
    const int* dst = ei + N_EDGES;

    float* out = (float*)d_out;
    float* h   = (float*)d_ws;                       // N*D floats = 51.2 MB
    float* dis = h + (size_t)N_NODES * D;            // N floats

    // degree -> dis (depends only on ew,dst; shared across all 3 layers)
    k_zero<<<(N_NODES + 255) / 256, 256, 0, stream>>>(dis, N_NODES);
    k_deg<<<(N_EDGES + 255) / 256, 256, 0, stream>>>(dst, ew, dis);
    k_dis<<<(N_NODES + 255) / 256, 256, 0, stream>>>(dis);

    const int gemm_blocks = N_NODES / TILE_ROWS;         // 3125 exactly
    const int edge_blocks = (N_EDGES * 64) / 256;        // 400000 exactly
    const int prelu_blocks = (N_NODES * (D / 4) + 255) / 256;

    // ----- layer 1 -----
    k_gemm_agginit<<<gemm_blocks, 256, 0, stream>>>(x, W1, b1, dis, h, out);
    k_edge<<<edge_blocks, 256, 0, stream>>>(src, dst, ew, dis, h, out);
    k_prelu<<<prelu_blocks, 256, 0, stream>>>(out, a1);
    // ----- layer 2 -----
    k_gemm_agginit<<<gemm_blocks, 256, 0, stream>>>(out, W2, b2, dis, h, out);
    k_edge<<<edge_blocks, 256, 0, stream>>>(src, dst, ew, dis, h, out);
    k_prelu<<<prelu_blocks, 256, 0, stream>>>(out, a2);
    // ----- layer 3 -----
    k_gemm_agginit<<<gemm_blocks, 256, 0, stream>>>(out, W3, b3, dis, h, out);
    k_edge<<<edge_blocks, 256, 0, stream>>>(src, dst, ew, dis, h, out);
    k_prelu<<<prelu_blocks, 256, 0, stream>>>(out, a3);
}

// Round 2
// 937.280 us; speedup vs baseline: 4.5291x; 4.5291x over previous
//
#include <hip/hip_runtime.h>

#define N_NODES 100000
#define N_EDGES 1600000
#define D 128
#define TILE_ROWS 32

// ---------------- utility ----------------

__global__ void k_zero_i(int* __restrict__ p, int n) {
    int i = blockIdx.x * blockDim.x + threadIdx.x;
    if (i < n) p[i] = 0;
}

// degree (float, weighted) + in-degree count (int) in one pass
__global__ void k_deg_count(const int* __restrict__ dst, const float* __restrict__ ew,
                            float* __restrict__ deg, int* __restrict__ cnt) {
    int i = blockIdx.x * blockDim.x + threadIdx.x;
    if (i < N_EDGES) {
        int t = dst[i];
        atomicAdd(&deg[t], ew[i]);
        atomicAdd(&cnt[t], 1);
    }
}

__global__ void k_dis(float* __restrict__ deg) {
    int i = blockIdx.x * blockDim.x + threadIdx.x;
    if (i < N_NODES) deg[i] = rsqrtf(deg[i] + 1.0f);  // self-loop weight 1
}

// ---------------- exclusive scan of cnt[N] -> rowptr ----------------
// 1024 elements per block (256 thr x 4), partials + block sums.
__global__ __launch_bounds__(256) void k_scan1(const int* __restrict__ cnt,
                                               int* __restrict__ rowptr,
                                               int* __restrict__ bsum) {
    __shared__ int sd[256];
    int t = threadIdx.x;
    int base = blockIdx.x * 1024 + t * 4;
    int v0 = base + 0 < N_NODES ? cnt[base + 0] : 0;
    int v1 = base + 1 < N_NODES ? cnt[base + 1] : 0;
    int v2 = base + 2 < N_NODES ? cnt[base + 2] : 0;
    int v3 = base + 3 < N_NODES ? cnt[base + 3] : 0;
    int lsum = v0 + v1 + v2 + v3;
    sd[t] = lsum;
    __syncthreads();
    // Hillis-Steele inclusive scan over 256 thread sums
    for (int off = 1; off < 256; off <<= 1) {
        int x = (t >= off) ? sd[t - off] : 0;
        __syncthreads();
        sd[t] += x;
        __syncthreads();
    }
    int excl = sd[t] - lsum;
    if (base + 0 < N_NODES) rowptr[base + 0] = excl;
    if (base + 1 < N_NODES) rowptr[base + 1] = excl + v0;
    if (base + 2 < N_NODES) rowptr[base + 2] = excl + v0 + v1;
    if (base + 3 < N_NODES) rowptr[base + 3] = excl + v0 + v1 + v2;
    if (t == 255) bsum[blockIdx.x] = sd[255];
}

__global__ void k_scan2(int* __restrict__ bsum, int nb) {
    // single thread: scan 98 block sums
    if (blockIdx.x == 0 && threadIdx.x == 0) {
        int total = 0;
        for (int b = 0; b < nb; ++b) { int x = bsum[b]; bsum[b] = total; total += x; }
    }
}

__global__ void k_scan3(int* __restrict__ rowptr, const int* __restrict__ bsum) {
    int i = blockIdx.x * blockDim.x + threadIdx.x;
    if (i < N_NODES) rowptr[i] += bsum[i >> 10];
    else if (i == N_NODES) rowptr[N_NODES] = N_EDGES;
}

// ---------------- scatter edges into CSR buckets ----------------
// edges[pos] = {src, bitcast(coef)} with coef = dis[s]*ew*dis[t]
__global__ void k_scatter(const int* __restrict__ src, const int* __restrict__ dst,
                          const float* __restrict__ ew, const float* __restrict__ dis,
                          const int* __restrict__ rowptr, int* __restrict__ cur,
                          int2* __restrict__ edges) {
    int e = blockIdx.x * blockDim.x + threadIdx.x;
    if (e >= N_EDGES) return;
    int s = src[e], t = dst[e];
    int pos = rowptr[t] + atomicAdd(&cur[t], 1);
    float coef = dis[s] * ew[e] * dis[t];
    edges[pos] = make_int2(s, __float_as_int(coef));
}

// ---------------- GEMM: h = x @ W ----------------
__global__ __launch_bounds__(256) void k_gemm(
    const float* __restrict__ x, const float* __restrict__ W, float* __restrict__ h)
{
    __shared__ float Wl[D * D];          // 64 KB
    __shared__ float Xl[TILE_ROWS * D];  // 16 KB

    const int tx = threadIdx.x;
    const int row0 = blockIdx.x * TILE_ROWS;

    for (int i = tx; i < (D * D) / 4; i += 256)
        ((float4*)Wl)[i] = ((const float4*)W)[i];
    const float4* xsrc = (const float4*)(x + (size_t)row0 * D);
    for (int i = tx; i < (TILE_ROWS * D) / 4; i += 256)
        ((float4*)Xl)[i] = xsrc[i];
    __syncthreads();

    const int cg = (tx & 31) * 4;
    const int rg = (tx >> 5) * 4;

    float acc[4][4] = {};
#pragma unroll 4
    for (int k = 0; k < D; ++k) {
        float4 w = *(const float4*)&Wl[k * D + cg];
#pragma unroll
        for (int ri = 0; ri < 4; ++ri) {
            float xv = Xl[(rg + ri) * D + k];
            acc[ri][0] += xv * w.x;
            acc[ri][1] += xv * w.y;
            acc[ri][2] += xv * w.z;
            acc[ri][3] += xv * w.w;
        }
    }

#pragma unroll
    for (int ri = 0; ri < 4; ++ri) {
        int r = row0 + rg + ri;
        *(float4*)&h[(size_t)r * D + cg] =
            make_float4(acc[ri][0], acc[ri][1], acc[ri][2], acc[ri][3]);
    }
}

// ---------------- gather: out[n] = prelu( sum coef*h[src] + dis^2*h[n] + b ) ----------------
// one 64-lane wave per node, float2 per lane
__global__ __launch_bounds__(256) void k_gather(
    const int* __restrict__ rowptr, const int2* __restrict__ edges,
    const float* __restrict__ h, const float* __restrict__ dis,
    const float* __restrict__ b, const float* __restrict__ alpha,
    float* __restrict__ out)
{
    int gid = blockIdx.x * 256 + threadIdx.x;
    int n = gid >> 6;
    if (n >= N_NODES) return;
    int d = (gid & 63) * 2;

    int beg = rowptr[n], end = rowptr[n + 1];
    float ax = 0.0f, ay = 0.0f;
    for (int e = beg; e < end; ++e) {
        int2 sc = edges[e];
        float c = __int_as_float(sc.y);
        float2 hv = *(const float2*)&h[(size_t)sc.x * D + d];
        ax = fmaf(c, hv.x, ax);
        ay = fmaf(c, hv.y, ay);
    }
    float di = dis[n];
    float d2 = di * di;
    float2 hv = *(const float2*)&h[(size_t)n * D + d];
    float2 bv = *(const float2*)&b[d];
    float2 av = *(const float2*)&alpha[d];
    float rx = ax + d2 * hv.x + bv.x;
    float ry = ay + d2 * hv.y + bv.y;
    rx = rx >= 0.0f ? rx : av.x * rx;
    ry = ry >= 0.0f ? ry : av.y * ry;
    *(float2*)&out[(size_t)n * D + d] = make_float2(rx, ry);
}

// ---------------- launch ----------------

extern "C" void kernel_launch(void* const* d_in, const int* in_sizes, int n_in,
                              void* d_out, int out_size, void* d_ws, size_t ws_size,
                              hipStream_t stream) {
    const float* x   = (const float*)d_in[0];
    const int*   ei  = (const int*)d_in[1];
    const float* ew  = (const float*)d_in[2];
    const float* W1  = (const float*)d_in[3];
    const float* b1  = (const float*)d_in[4];
    const float* a1  = (const float*)d_in[5];
    const float* W2  = (const float*)d_in[6];
    const float* b2  = (const float*)d_in[7];
    const float* a2  = (const float*)d_in[8];
    const float* W3  = (const float*)d_in[9];
    const float* b3  = (const float*)d_in[10];
    const float* a3  = (const float*)d_in[11];

    const int* src = ei;
    const int* dst = ei + N_EDGES;

    float* out = (float*)d_out;

    // workspace layout
    float* h      = (float*)d_ws;                          // N*D floats (51.2 MB)
    int2*  edges  = (int2*)(h + (size_t)N_NODES * D);      // E int2 (12.8 MB)
    float* dis    = (float*)(edges + N_EDGES);             // N floats (doubles as deg)
    int*   cnt    = (int*)(dis + N_NODES);                 // N
    int*   cur    = cnt + N_NODES;                         // N
    int*   rowptr = cur + N_NODES;                         // N+1
    int*   bsum   = rowptr + N_NODES + 1;                  // 128

    const int nb_scan = (N_NODES + 1023) / 1024;           // 98

    // zero deg(float) + cnt + cur: contiguous 3N ints
    k_zero_i<<<(3 * N_NODES + 255) / 256, 256, 0, stream>>>((int*)dis, 3 * N_NODES);
    k_deg_count<<<(N_EDGES + 255) / 256, 256, 0, stream>>>(dst, ew, dis, cnt);
    k_dis<<<(N_NODES + 255) / 256, 256, 0, stream>>>(dis);
    k_scan1<<<nb_scan, 256, 0, stream>>>(cnt, rowptr, bsum);
    k_scan2<<<1, 1, 0, stream>>>(bsum, nb_scan);
    k_scan3<<<(N_NODES + 256) / 256, 256, 0, stream>>>(rowptr, bsum);
    k_scatter<<<(N_EDGES + 255) / 256, 256, 0, stream>>>(src, dst, ew, dis, rowptr, cur, edges);

    const int gemm_blocks   = N_NODES / TILE_ROWS;             // 3125
    const int gather_blocks = (N_NODES * 64) / 256;            // 25000

    // ----- layer 1 -----
    k_gemm<<<gemm_blocks, 256, 0, stream>>>(x, W1, h);
    k_gather<<<gather_blocks, 256, 0, stream>>>(rowptr, edges, h, dis, b1, a1, out);
    // ----- layer 2 -----
    k_gemm<<<gemm_blocks, 256, 0, stream>>>(out, W2, h);
    k_gather<<<gather_blocks, 256, 0, stream>>>(rowptr, edges, h, dis, b2, a2, out);
    // ----- layer 3 -----
    k_gemm<<<gemm_blocks, 256, 0, stream>>>(out, W3, h);
    k_gather<<<gather_blocks, 256, 0, stream>>>(rowptr, edges, h, dis, b3, a3, out);
}

// Round 3
// 725.331 us; speedup vs baseline: 5.8526x; 1.2922x over previous
//
#include <hip/hip_runtime.h>

#define N_NODES 100000
#define N_EDGES 1600000
#define D 128
#define TILE_ROWS 32

typedef unsigned int uint;

__device__ inline ushort f2bf(float f) {  // RTNE bf16 (finite inputs)
    union { float f; uint u; } v; v.f = f;
    uint r = v.u + 0x7fffu + ((v.u >> 16) & 1u);
    return (ushort)(r >> 16);
}

// ---------------- utility ----------------

__global__ void k_zero_i(int* __restrict__ p, int n) {
    int i = blockIdx.x * blockDim.x + threadIdx.x;
    if (i < n) p[i] = 0;
}

__global__ void k_deg_count(const int* __restrict__ dst, const float* __restrict__ ew,
                            float* __restrict__ deg, int* __restrict__ cnt) {
    int i = blockIdx.x * blockDim.x + threadIdx.x;
    if (i < N_EDGES) {
        int t = dst[i];
        atomicAdd(&deg[t], ew[i]);
        atomicAdd(&cnt[t], 1);
    }
}

__global__ void k_dis(float* __restrict__ deg) {
    int i = blockIdx.x * blockDim.x + threadIdx.x;
    if (i < N_NODES) deg[i] = rsqrtf(deg[i] + 1.0f);
}

// ---------------- exclusive scan of cnt[N] -> rowptr ----------------
__global__ __launch_bounds__(256) void k_scan1(const int* __restrict__ cnt,
                                               int* __restrict__ rowptr,
                                               int* __restrict__ bsum) {
    __shared__ int sd[256];
    int t = threadIdx.x;
    int base = blockIdx.x * 1024 + t * 4;
    int v0 = base + 0 < N_NODES ? cnt[base + 0] : 0;
    int v1 = base + 1 < N_NODES ? cnt[base + 1] : 0;
    int v2 = base + 2 < N_NODES ? cnt[base + 2] : 0;
    int v3 = base + 3 < N_NODES ? cnt[base + 3] : 0;
    int lsum = v0 + v1 + v2 + v3;
    sd[t] = lsum;
    __syncthreads();
    for (int off = 1; off < 256; off <<= 1) {
        int x = (t >= off) ? sd[t - off] : 0;
        __syncthreads();
        sd[t] += x;
        __syncthreads();
    }
    int excl = sd[t] - lsum;
    if (base + 0 < N_NODES) rowptr[base + 0] = excl;
    if (base + 1 < N_NODES) rowptr[base + 1] = excl + v0;
    if (base + 2 < N_NODES) rowptr[base + 2] = excl + v0 + v1;
    if (base + 3 < N_NODES) rowptr[base + 3] = excl + v0 + v1 + v2;
    if (t == 255) bsum[blockIdx.x] = sd[255];
}

__global__ void k_scan2(int* __restrict__ bsum, int nb) {
    if (blockIdx.x == 0 && threadIdx.x == 0) {
        int total = 0;
        for (int b = 0; b < nb; ++b) { int x = bsum[b]; bsum[b] = total; total += x; }
    }
}

__global__ void k_scan3(int* __restrict__ rowptr, const int* __restrict__ bsum) {
    int i = blockIdx.x * blockDim.x + threadIdx.x;
    if (i < N_NODES) rowptr[i] += bsum[i >> 10];
    else if (i == N_NODES) rowptr[N_NODES] = N_EDGES;
}

// ---------------- scatter edges into CSR buckets ----------------
__global__ void k_scatter(const int* __restrict__ src, const int* __restrict__ dst,
                          const float* __restrict__ ew, const float* __restrict__ dis,
                          const int* __restrict__ rowptr, int* __restrict__ cur,
                          int2* __restrict__ edges) {
    int e = blockIdx.x * blockDim.x + threadIdx.x;
    if (e >= N_EDGES) return;
    int s = src[e], t = dst[e];
    int pos = rowptr[t] + atomicAdd(&cur[t], 1);
    float coef = dis[s] * ew[e] * dis[t];
    edges[pos] = make_int2(s, __float_as_int(coef));
}

// ---------------- GEMM: h(bf16) = x @ W ----------------
// all-b128 LDS reads: k unrolled by 4; X row reads are half-wave-broadcast.
__global__ __launch_bounds__(256) void k_gemm(
    const float* __restrict__ x, const float* __restrict__ W, ushort* __restrict__ hb)
{
    __shared__ float Wl[D * D];          // 64 KB
    __shared__ float Xl[TILE_ROWS * D];  // 16 KB

    const int tx = threadIdx.x;
    const int row0 = blockIdx.x * TILE_ROWS;

    for (int i = tx; i < (D * D) / 4; i += 256)
        ((float4*)Wl)[i] = ((const float4*)W)[i];
    const float4* xsrc = (const float4*)(x + (size_t)row0 * D);
    for (int i = tx; i < (TILE_ROWS * D) / 4; i += 256)
        ((float4*)Xl)[i] = xsrc[i];
    __syncthreads();

    const int cg = (tx & 31) * 4;
    const int rg = (tx >> 5) * 4;

    float acc[4][4] = {};
    for (int k = 0; k < D; k += 4) {
        float4 w0 = *(const float4*)&Wl[(k + 0) * D + cg];
        float4 w1 = *(const float4*)&Wl[(k + 1) * D + cg];
        float4 w2 = *(const float4*)&Wl[(k + 2) * D + cg];
        float4 w3 = *(const float4*)&Wl[(k + 3) * D + cg];
#pragma unroll
        for (int ri = 0; ri < 4; ++ri) {
            float4 xv = *(const float4*)&Xl[(rg + ri) * D + k];
            acc[ri][0] += xv.x * w0.x + xv.y * w1.x + xv.z * w2.x + xv.w * w3.x;
            acc[ri][1] += xv.x * w0.y + xv.y * w1.y + xv.z * w2.y + xv.w * w3.y;
            acc[ri][2] += xv.x * w0.z + xv.y * w1.z + xv.z * w2.z + xv.w * w3.z;
            acc[ri][3] += xv.x * w0.w + xv.y * w1.w + xv.z * w2.w + xv.w * w3.w;
        }
    }

#pragma unroll
    for (int ri = 0; ri < 4; ++ri) {
        int r = row0 + rg + ri;
        ushort4 o;
        o.x = f2bf(acc[ri][0]); o.y = f2bf(acc[ri][1]);
        o.z = f2bf(acc[ri][2]); o.w = f2bf(acc[ri][3]);
        *(ushort4*)&hb[(size_t)r * D + cg] = o;
    }
}

// ---------------- gather: out[n] = prelu( sum coef*h[src] + dis^2*h[n] + b ) ----------------
// one wave per node; 4 edges in flight (16 lanes each, uint4 = 8 bf16/lane).
__global__ __launch_bounds__(256) void k_gather(
    const int* __restrict__ rowptr, const int2* __restrict__ edges,
    const ushort* __restrict__ hb, const float* __restrict__ dis,
    const float* __restrict__ b, const float* __restrict__ alpha,
    float* __restrict__ out)
{
    int gid = blockIdx.x * 256 + threadIdx.x;
    int n = gid >> 6;
    if (n >= N_NODES) return;
    int lane = gid & 63;
    int q = lane >> 4;           // edge slot 0..3
    int c0 = (lane & 15) * 8;    // 8 cols per lane

    int beg = rowptr[n], end = rowptr[n + 1];
    float acc[8] = {0.f, 0.f, 0.f, 0.f, 0.f, 0.f, 0.f, 0.f};

    for (int e = beg + q; e < end; e += 4) {
        int2 sc = edges[e];
        float c = __int_as_float(sc.y);
        uint4 hv = *(const uint4*)&hb[(size_t)sc.x * D + c0];
#pragma unroll
        for (int j = 0; j < 4; ++j) {
            uint w = ((const uint*)&hv)[j];
            float lo = __uint_as_float(w << 16);
            float hi = __uint_as_float(w & 0xffff0000u);
            acc[2 * j]     = fmaf(c, lo, acc[2 * j]);
            acc[2 * j + 1] = fmaf(c, hi, acc[2 * j + 1]);
        }
    }

    // combine the 4 edge slots (lanes l, l^16, l^32, l^48 share cols)
#pragma unroll
    for (int j = 0; j < 8; ++j) {
        acc[j] += __shfl_xor(acc[j], 16);
        acc[j] += __shfl_xor(acc[j], 32);
    }

    if (q == 0) {
        float di = dis[n];
        float d2 = di * di;
        uint4 hv = *(const uint4*)&hb[(size_t)n * D + c0];
        float r[8];
#pragma unroll
        for (int j = 0; j < 4; ++j) {
            uint w = ((const uint*)&hv)[j];
            float lo = __uint_as_float(w << 16);
            float hi = __uint_as_float(w & 0xffff0000u);
            r[2 * j]     = acc[2 * j]     + d2 * lo + b[c0 + 2 * j];
            r[2 * j + 1] = acc[2 * j + 1] + d2 * hi + b[c0 + 2 * j + 1];
        }
#pragma unroll
        for (int j = 0; j < 8; ++j) {
            float av = alpha[c0 + j];
            r[j] = r[j] >= 0.f ? r[j] : av * r[j];
        }
        *(float4*)&out[(size_t)n * D + c0]     = make_float4(r[0], r[1], r[2], r[3]);
        *(float4*)&out[(size_t)n * D + c0 + 4] = make_float4(r[4], r[5], r[6], r[7]);
    }
}

// ---------------- launch ----------------

extern "C" void kernel_launch(void* const* d_in, const int* in_sizes, int n_in,
                              void* d_out, int out_size, void* d_ws, size_t ws_size,
                              hipStream_t stream) {
    const float* x   = (const float*)d_in[0];
    const int*   ei  = (const int*)d_in[1];
    const float* ew  = (const float*)d_in[2];
    const float* W1  = (const float*)d_in[3];
    const float* b1  = (const float*)d_in[4];
    const float* a1  = (const float*)d_in[5];
    const float* W2  = (const float*)d_in[6];
    const float* b2  = (const float*)d_in[7];
    const float* a2  = (const float*)d_in[8];
    const float* W3  = (const float*)d_in[9];
    const float* b3  = (const float*)d_in[10];
    const float* a3  = (const float*)d_in[11];

    const int* src = ei;
    const int* dst = ei + N_EDGES;

    float* out = (float*)d_out;

    // workspace layout
    ushort* hb    = (ushort*)d_ws;                         // N*D bf16 (25.6 MB)
    int2*   edges = (int2*)(hb + (size_t)N_NODES * D);     // E int2 (12.8 MB)
    float*  dis   = (float*)(edges + N_EDGES);             // N floats (doubles as deg)
    int*    cnt   = (int*)(dis + N_NODES);
    int*    cur   = cnt + N_NODES;
    int*    rowptr = cur + N_NODES;                        // N+1
    int*    bsum  = rowptr + N_NODES + 1;                  // 128

    const int nb_scan = (N_NODES + 1023) / 1024;

    k_zero_i<<<(3 * N_NODES + 255) / 256, 256, 0, stream>>>((int*)dis, 3 * N_NODES);
    k_deg_count<<<(N_EDGES + 255) / 256, 256, 0, stream>>>(dst, ew, dis, cnt);
    k_dis<<<(N_NODES + 255) / 256, 256, 0, stream>>>(dis);
    k_scan1<<<nb_scan, 256, 0, stream>>>(cnt, rowptr, bsum);
    k_scan2<<<1, 1, 0, stream>>>(bsum, nb_scan);
    k_scan3<<<(N_NODES + 256) / 256, 256, 0, stream>>>(rowptr, bsum);
    k_scatter<<<(N_EDGES + 255) / 256, 256, 0, stream>>>(src, dst, ew, dis, rowptr, cur, edges);

    const int gemm_blocks   = N_NODES / TILE_ROWS;   // 3125
    const int gather_blocks = (N_NODES * 64) / 256;  // 25000

    // ----- layer 1 -----
    k_gemm<<<gemm_blocks, 256, 0, stream>>>(x, W1, hb);
    k_gather<<<gather_blocks, 256, 0, stream>>>(rowptr, edges, hb, dis, b1, a1, out);
    // ----- layer 2 -----
    k_gemm<<<gemm_blocks, 256, 0, stream>>>(out, W2, hb);
    k_gather<<<gather_blocks, 256, 0, stream>>>(rowptr, edges, hb, dis, b2, a2, out);
    // ----- layer 3 -----
    k_gemm<<<gemm_blocks, 256, 0, stream>>>(out, W3, hb);
    k_gather<<<gather_blocks, 256, 0, stream>>>(rowptr, edges, hb, dis, b3, a3, out);
}

// Round 4
// 666.476 us; speedup vs baseline: 6.3694x; 1.0883x over previous
//
#include <hip/hip_runtime.h>

#define N_NODES 100000
#define N_EDGES 1600000
#define D 128
#define TILE_ROWS 32

typedef unsigned int uint;
typedef unsigned long long u64;

__device__ inline ushort f2bf(float f) {  // RTNE bf16 (finite inputs)
    union { float f; uint u; } v; v.f = f;
    uint r = v.u + 0x7fffu + ((v.u >> 16) & 1u);
    return (ushort)(r >> 16);
}

// ---------------- utility ----------------

__global__ void k_zero_i(int* __restrict__ p, int n) {
    int i = blockIdx.x * blockDim.x + threadIdx.x;
    if (i < n) p[i] = 0;
}

// packed per-node accumulator: bits [63:40] = in-degree count, [39:0] = sum(ew) in Q31
__global__ void k_pack(const int* __restrict__ dst, const float* __restrict__ ew,
                       u64* __restrict__ packed) {
    int i = blockIdx.x * blockDim.x + threadIdx.x;
    if (i < N_EDGES) {
        u64 v = (1ULL << 40) | (u64)llrintf(ew[i] * 2147483648.0f);
        atomicAdd(&packed[dst[i]], v);
    }
}

// ---------------- scan1: unpack (deg->dis, cnt) + block-local exclusive scan ----------------
__global__ __launch_bounds__(256) void k_scan1(const u64* __restrict__ packed,
                                               float* __restrict__ dis,
                                               int* __restrict__ rowptr,
                                               int* __restrict__ bsum) {
    __shared__ int sd[256];
    int t = threadIdx.x;
    int base = blockIdx.x * 1024 + t * 4;
    int v[4];
#pragma unroll
    for (int j = 0; j < 4; ++j) {
        int idx = base + j;
        int c = 0;
        if (idx < N_NODES) {
            u64 p = packed[idx];
            c = (int)(p >> 40);
            float deg = (float)((double)(p & 0xFFFFFFFFFFULL) * (1.0 / 2147483648.0));
            dis[idx] = rsqrtf(deg + 1.0f);   // self-loop weight 1
        }
        v[j] = c;
    }
    int lsum = v[0] + v[1] + v[2] + v[3];
    sd[t] = lsum;
    __syncthreads();
    for (int off = 1; off < 256; off <<= 1) {
        int x = (t >= off) ? sd[t - off] : 0;
        __syncthreads();
        sd[t] += x;
        __syncthreads();
    }
    int excl = sd[t] - lsum;
    if (base + 0 < N_NODES) rowptr[base + 0] = excl;
    if (base + 1 < N_NODES) rowptr[base + 1] = excl + v[0];
    if (base + 2 < N_NODES) rowptr[base + 2] = excl + v[0] + v[1];
    if (base + 3 < N_NODES) rowptr[base + 3] = excl + v[0] + v[1] + v[2];
    if (t == 255) bsum[blockIdx.x] = sd[255];
}

__global__ void k_scan2(int* __restrict__ bsum, int nb) {
    if (blockIdx.x == 0 && threadIdx.x == 0) {
        int total = 0;
        for (int b = 0; b < nb; ++b) { int x = bsum[b]; bsum[b] = total; total += x; }
    }
}

__global__ void k_scan3(int* __restrict__ rowptr, int* __restrict__ rowptr_mut,
                        const int* __restrict__ bsum) {
    int i = blockIdx.x * blockDim.x + threadIdx.x;
    if (i < N_NODES) {
        int v = rowptr[i] + bsum[i >> 10];
        rowptr[i] = v;
        rowptr_mut[i] = v;
    } else if (i == N_NODES) {
        rowptr[N_NODES] = N_EDGES;
    }
}

// ---------------- scatter edges into CSR buckets ----------------
__global__ void k_scatter(const int* __restrict__ src, const int* __restrict__ dst,
                          const float* __restrict__ ew, const float* __restrict__ dis,
                          int* __restrict__ rowptr_mut, int2* __restrict__ edges) {
    int e = blockIdx.x * blockDim.x + threadIdx.x;
    if (e >= N_EDGES) return;
    int s = src[e], t = dst[e];
    int pos = atomicAdd(&rowptr_mut[t], 1);
    float coef = dis[s] * ew[e] * dis[t];
    edges[pos] = make_int2(s, __float_as_int(coef));
}

// ---------------- GEMM: h(bf16) = x @ W ----------------
__global__ __launch_bounds__(256) void k_gemm(
    const float* __restrict__ x, const float* __restrict__ W, ushort* __restrict__ hb)
{
    __shared__ float Wl[D * D];          // 64 KB
    __shared__ float Xl[TILE_ROWS * D];  // 16 KB

    const int tx = threadIdx.x;
    const int row0 = blockIdx.x * TILE_ROWS;

    for (int i = tx; i < (D * D) / 4; i += 256)
        ((float4*)Wl)[i] = ((const float4*)W)[i];
    const float4* xsrc = (const float4*)(x + (size_t)row0 * D);
    for (int i = tx; i < (TILE_ROWS * D) / 4; i += 256)
        ((float4*)Xl)[i] = xsrc[i];
    __syncthreads();

    const int cg = (tx & 31) * 4;
    const int rg = (tx >> 5) * 4;

    float acc[4][4] = {};
    for (int k = 0; k < D; k += 4) {
        float4 w0 = *(const float4*)&Wl[(k + 0) * D + cg];
        float4 w1 = *(const float4*)&Wl[(k + 1) * D + cg];
        float4 w2 = *(const float4*)&Wl[(k + 2) * D + cg];
        float4 w3 = *(const float4*)&Wl[(k + 3) * D + cg];
#pragma unroll
        for (int ri = 0; ri < 4; ++ri) {
            float4 xv = *(const float4*)&Xl[(rg + ri) * D + k];
            acc[ri][0] += xv.x * w0.x + xv.y * w1.x + xv.z * w2.x + xv.w * w3.x;
            acc[ri][1] += xv.x * w0.y + xv.y * w1.y + xv.z * w2.y + xv.w * w3.y;
            acc[ri][2] += xv.x * w0.z + xv.y * w1.z + xv.z * w2.z + xv.w * w3.z;
            acc[ri][3] += xv.x * w0.w + xv.y * w1.w + xv.z * w2.w + xv.w * w3.w;
        }
    }

#pragma unroll
    for (int ri = 0; ri < 4; ++ri) {
        int r = row0 + rg + ri;
        ushort4 o;
        o.x = f2bf(acc[ri][0]); o.y = f2bf(acc[ri][1]);
        o.z = f2bf(acc[ri][2]); o.w = f2bf(acc[ri][3]);
        *(ushort4*)&hb[(size_t)r * D + cg] = o;
    }
}

// ---------------- gather: out[n] = prelu( sum coef*h[src] + dis^2*h[n] + b ) ----------------
__global__ __launch_bounds__(256) void k_gather(
    const int* __restrict__ rowptr, const int2* __restrict__ edges,
    const ushort* __restrict__ hb, const float* __restrict__ dis,
    const float* __restrict__ b, const float* __restrict__ alpha,
    float* __restrict__ out)
{
    int gid = blockIdx.x * 256 + threadIdx.x;
    int n = gid >> 6;
    if (n >= N_NODES) return;
    int lane = gid & 63;
    int q = lane >> 4;           // edge slot 0..3
    int c0 = (lane & 15) * 8;    // 8 cols per lane

    int beg = rowptr[n], end = rowptr[n + 1];
    float acc[8] = {0.f, 0.f, 0.f, 0.f, 0.f, 0.f, 0.f, 0.f};

    for (int e = beg + q; e < end; e += 4) {
        int2 sc = edges[e];
        float c = __int_as_float(sc.y);
        uint4 hv = *(const uint4*)&hb[(size_t)sc.x * D + c0];
#pragma unroll
        for (int j = 0; j < 4; ++j) {
            uint w = ((const uint*)&hv)[j];
            float lo = __uint_as_float(w << 16);
            float hi = __uint_as_float(w & 0xffff0000u);
            acc[2 * j]     = fmaf(c, lo, acc[2 * j]);
            acc[2 * j + 1] = fmaf(c, hi, acc[2 * j + 1]);
        }
    }

#pragma unroll
    for (int j = 0; j < 8; ++j) {
        acc[j] += __shfl_xor(acc[j], 16);
        acc[j] += __shfl_xor(acc[j], 32);
    }

    if (q == 0) {
        float di = dis[n];
        float d2 = di * di;
        uint4 hv = *(const uint4*)&hb[(size_t)n * D + c0];
        float r[8];
#pragma unroll
        for (int j = 0; j < 4; ++j) {
            uint w = ((const uint*)&hv)[j];
            float lo = __uint_as_float(w << 16);
            float hi = __uint_as_float(w & 0xffff0000u);
            r[2 * j]     = acc[2 * j]     + d2 * lo + b[c0 + 2 * j];
            r[2 * j + 1] = acc[2 * j + 1] + d2 * hi + b[c0 + 2 * j + 1];
        }
#pragma unroll
        for (int j = 0; j < 8; ++j) {
            float av = alpha[c0 + j];
            r[j] = r[j] >= 0.f ? r[j] : av * r[j];
        }
        *(float4*)&out[(size_t)n * D + c0]     = make_float4(r[0], r[1], r[2], r[3]);
        *(float4*)&out[(size_t)n * D + c0 + 4] = make_float4(r[4], r[5], r[6], r[7]);
    }
}

// ---------------- launch ----------------

extern "C" void kernel_launch(void* const* d_in, const int* in_sizes, int n_in,
                              void* d_out, int out_size, void* d_ws, size_t ws_size,
                              hipStream_t stream) {
    const float* x   = (const float*)d_in[0];
    const int*   ei  = (const int*)d_in[1];
    const float* ew  = (const float*)d_in[2];
    const float* W1  = (const float*)d_in[3];
    const float* b1  = (const float*)d_in[4];
    const float* a1  = (const float*)d_in[5];
    const float* W2  = (const float*)d_in[6];
    const float* b2  = (const float*)d_in[7];
    const float* a2  = (const float*)d_in[8];
    const float* W3  = (const float*)d_in[9];
    const float* b3  = (const float*)d_in[10];
    const float* a3  = (const float*)d_in[11];

    const int* src = ei;
    const int* dst = ei + N_EDGES;

    float* out = (float*)d_out;

    // workspace layout (8-byte alignment maintained)
    ushort* hb        = (ushort*)d_ws;                          // N*D bf16 (25.6 MB)
    int2*   edges     = (int2*)(hb + (size_t)N_NODES * D);      // E int2 (12.8 MB)
    u64*    packed    = (u64*)(edges + N_EDGES);                // N u64 (800 KB)
    float*  dis       = (float*)(packed + N_NODES);             // N floats
    int*    rowptr    = (int*)(dis + N_NODES);                  // N+1
    int*    rowptr_mut= rowptr + N_NODES + 1;                   // N+1
    int*    bsum      = rowptr_mut + N_NODES + 1;               // 128

    const int nb_scan = (N_NODES + 1023) / 1024;  // 98

    k_zero_i<<<(2 * N_NODES + 255) / 256, 256, 0, stream>>>((int*)packed, 2 * N_NODES);
    k_pack<<<(N_EDGES + 255) / 256, 256, 0, stream>>>(dst, ew, packed);
    k_scan1<<<nb_scan, 256, 0, stream>>>(packed, dis, rowptr, bsum);
    k_scan2<<<1, 1, 0, stream>>>(bsum, nb_scan);
    k_scan3<<<(N_NODES + 256) / 256, 256, 0, stream>>>(rowptr, rowptr_mut, bsum);
    k_scatter<<<(N_EDGES + 255) / 256, 256, 0, stream>>>(src, dst, ew, dis, rowptr_mut, edges);

    const int gemm_blocks   = N_NODES / TILE_ROWS;   // 3125
    const int gather_blocks = (N_NODES * 64) / 256;  // 25000

    // ----- layer 1 -----
    k_gemm<<<gemm_blocks, 256, 0, stream>>>(x, W1, hb);
    k_gather<<<gather_blocks, 256, 0, stream>>>(rowptr, edges, hb, dis, b1, a1, out);
    // ----- layer 2 -----
    k_gemm<<<gemm_blocks, 256, 0, stream>>>(out, W2, hb);
    k_gather<<<gather_blocks, 256, 0, stream>>>(rowptr, edges, hb, dis, b2, a2, out);
    // ----- layer 3 -----
    k_gemm<<<gemm_blocks, 256, 0, stream>>>(out, W3, hb);
    k_gather<<<gather_blocks, 256, 0, stream>>>(rowptr, edges, hb, dis, b3, a3, out);
}

// Round 5
// 548.344 us; speedup vs baseline: 7.7416x; 1.2154x over previous
//
#include <hip/hip_runtime.h>

#define N_NODES 100000
#define N_EDGES 1600000
#define D 128
#define TILE_ROWS 32

typedef unsigned int uint;
typedef unsigned long long u64;
typedef short short8 __attribute__((ext_vector_type(8)));
typedef float f32x4 __attribute__((ext_vector_type(4)));

__device__ inline ushort f2bf(float f) {  // RTNE bf16 (finite inputs)
    union { float f; uint u; } v; v.f = f;
    uint r = v.u + 0x7fffu + ((v.u >> 16) & 1u);
    return (ushort)(r >> 16);
}
__device__ inline float bf2f(ushort b) {
    union { uint u; float f; } v; v.u = ((uint)b) << 16;
    return v.f;
}

// ---------------- utility ----------------

__global__ void k_zero_i(int* __restrict__ p, int n) {
    int i = blockIdx.x * blockDim.x + threadIdx.x;
    if (i < n) p[i] = 0;
}

// packed per-node accumulator: bits [63:40] = in-degree count, [39:0] = sum(ew) in Q31
__global__ void k_pack(const int* __restrict__ dst, const float* __restrict__ ew,
                       u64* __restrict__ packed) {
    int i = blockIdx.x * blockDim.x + threadIdx.x;
    if (i < N_EDGES) {
        u64 v = (1ULL << 40) | (u64)llrintf(ew[i] * 2147483648.0f);
        atomicAdd(&packed[dst[i]], v);
    }
}

// ---------------- W split: fp32 W[k][c] -> bf16 hi/lo, transposed + swizzled ----------------
// Wht/Wlt layout: ushort index c*128 + ((j ^ (c&7))<<3 | (k&7)), j = k>>3  (16B chunks)
__global__ void k_wsplit(const float* __restrict__ W, ushort* __restrict__ Wht,
                         ushort* __restrict__ Wlt) {
    int i = blockIdx.x * 256 + threadIdx.x;   // 16384
    int k = i >> 7, c = i & 127;
    float w = W[i];
    ushort wh = f2bf(w);
    ushort wl = f2bf(w - bf2f(wh));
    int j = k >> 3;
    int off = c * 128 + (((j ^ (c & 7)) << 3) | (k & 7));
    Wht[off] = wh;
    Wlt[off] = wl;
}

// ---------------- scan1: unpack (deg->dis, cnt) + block-local exclusive scan ----------------
__global__ __launch_bounds__(256) void k_scan1(const u64* __restrict__ packed,
                                               float* __restrict__ dis,
                                               int* __restrict__ rowptr,
                                               int* __restrict__ bsum) {
    __shared__ int sd[256];
    int t = threadIdx.x;
    int base = blockIdx.x * 1024 + t * 4;
    int v[4];
#pragma unroll
    for (int j = 0; j < 4; ++j) {
        int idx = base + j;
        int c = 0;
        if (idx < N_NODES) {
            u64 p = packed[idx];
            c = (int)(p >> 40);
            float deg = (float)((double)(p & 0xFFFFFFFFFFULL) * (1.0 / 2147483648.0));
            dis[idx] = rsqrtf(deg + 1.0f);   // self-loop weight 1
        }
        v[j] = c;
    }
    int lsum = v[0] + v[1] + v[2] + v[3];
    sd[t] = lsum;
    __syncthreads();
    for (int off = 1; off < 256; off <<= 1) {
        int x = (t >= off) ? sd[t - off] : 0;
        __syncthreads();
        sd[t] += x;
        __syncthreads();
    }
    int excl = sd[t] - lsum;
    if (base + 0 < N_NODES) rowptr[base + 0] = excl;
    if (base + 1 < N_NODES) rowptr[base + 1] = excl + v[0];
    if (base + 2 < N_NODES) rowptr[base + 2] = excl + v[0] + v[1];
    if (base + 3 < N_NODES) rowptr[base + 3] = excl + v[0] + v[1] + v[2];
    if (t == 255) bsum[blockIdx.x] = sd[255];
}

__global__ void k_scan2(int* __restrict__ bsum, int nb) {
    if (blockIdx.x == 0 && threadIdx.x == 0) {
        int total = 0;
        for (int b = 0; b < nb; ++b) { int x = bsum[b]; bsum[b] = total; total += x; }
    }
}

__global__ void k_scan3(int* __restrict__ rowptr, int* __restrict__ rowptr_mut,
                        const int* __restrict__ bsum) {
    int i = blockIdx.x * blockDim.x + threadIdx.x;
    if (i < N_NODES) {
        int v = rowptr[i] + bsum[i >> 10];
        rowptr[i] = v;
        rowptr_mut[i] = v;
    } else if (i == N_NODES) {
        rowptr[N_NODES] = N_EDGES;
    }
}

// ---------------- scatter edges into CSR buckets ----------------
__global__ void k_scatter(const int* __restrict__ src, const int* __restrict__ dst,
                          const float* __restrict__ ew, const float* __restrict__ dis,
                          int* __restrict__ rowptr_mut, int2* __restrict__ edges) {
    int e = blockIdx.x * blockDim.x + threadIdx.x;
    if (e >= N_EDGES) return;
    int s = src[e], t = dst[e];
    int pos = atomicAdd(&rowptr_mut[t], 1);
    float coef = dis[s] * ew[e] * dis[t];
    edges[pos] = make_int2(s, __float_as_int(coef));
}

// ---------------- MFMA GEMM: h(bf16) = x(fp32) @ W via 3-term bf16 split ----------------
// block = 256 thr (4 waves), tile 32 rows x 128 cols, K=128.
// h = xh@Wh + xl@Wh + xh@Wl  (residual ~2^-17 rel)
__global__ __launch_bounds__(256) void k_gemm_mfma(
    const float* __restrict__ x, const ushort* __restrict__ Wht,
    const ushort* __restrict__ Wlt, ushort* __restrict__ hb)
{
    __shared__ ushort WH[16384];   // 32 KB  (B hi, transposed+swizzled)
    __shared__ ushort WL[16384];   // 32 KB
    __shared__ ushort XH[4096];    // 8 KB   (A hi, swizzled)
    __shared__ ushort XL[4096];    // 8 KB

    const int tx = threadIdx.x;
    const int row0 = blockIdx.x * TILE_ROWS;

    // stage Wh/Wl (global layout already transposed+swizzled) : uint4 linear copy
    for (int i = tx; i < 2048; i += 256) {
        ((uint4*)WH)[i] = ((const uint4*)Wht)[i];
        ((uint4*)WL)[i] = ((const uint4*)Wlt)[i];
    }

    // split x tile into XH/XL: each thread converts 2 chunks of 8 floats
    {
        int m = tx * 2;                  // chunk id (512 chunks = 32 rows x 16)
        int r = m >> 4;
        int jb = m & 15;
        const float* xp = x + (size_t)(row0 + r) * D;
#pragma unroll
        for (int c = 0; c < 2; ++c) {
            int j = jb + c;
            float4 a0 = *(const float4*)(xp + j * 8);
            float4 a1 = *(const float4*)(xp + j * 8 + 4);
            float v[8] = {a0.x, a0.y, a0.z, a0.w, a1.x, a1.y, a1.z, a1.w};
            uint4 uh, ul;
            uint* ph = (uint*)&uh; uint* pl = (uint*)&ul;
#pragma unroll
            for (int e = 0; e < 4; ++e) {
                ushort h0 = f2bf(v[2 * e]),     h1 = f2bf(v[2 * e + 1]);
                ushort l0 = f2bf(v[2 * e] - bf2f(h0));
                ushort l1 = f2bf(v[2 * e + 1] - bf2f(h1));
                ph[e] = (uint)h0 | ((uint)h1 << 16);
                pl[e] = (uint)l0 | ((uint)l1 << 16);
            }
            int off = r * 16 + (j ^ (r & 7));   // uint4 units
            ((uint4*)XH)[off] = uh;
            ((uint4*)XL)[off] = ul;
        }
    }
    __syncthreads();

    const int wv = tx >> 6;          // wave 0..3 -> col block wv*32
    const int lane = tx & 63;
    const int lr = lane & 15;        // A row / B col (low)
    const int g = lane >> 4;         // k-group 0..3

    f32x4 acc[2][2] = {};            // [rowtile][coltile]

    const int c0 = wv * 32 + lr;     // (c0 & 7) == (lr & 7) since 32|8
    const int c1 = c0 + 16;

#pragma unroll
    for (int ks = 0; ks < 4; ++ks) {
        int co = ((ks * 4 + g) ^ (lr & 7)) << 3;   // swizzled chunk offset (ushorts)
        short8 ah0 = *(short8*)&XH[lr * 128 + co];
        short8 ah1 = *(short8*)&XH[(16 + lr) * 128 + co];
        short8 al0 = *(short8*)&XL[lr * 128 + co];
        short8 al1 = *(short8*)&XL[(16 + lr) * 128 + co];
        short8 bh0 = *(short8*)&WH[c0 * 128 + co];
        short8 bh1 = *(short8*)&WH[c1 * 128 + co];
        short8 bl0 = *(short8*)&WL[c0 * 128 + co];
        short8 bl1 = *(short8*)&WL[c1 * 128 + co];

        acc[0][0] = __builtin_amdgcn_mfma_f32_16x16x32_bf16(ah0, bh0, acc[0][0], 0, 0, 0);
        acc[0][1] = __builtin_amdgcn_mfma_f32_16x16x32_bf16(ah0, bh1, acc[0][1], 0, 0, 0);
        acc[1][0] = __builtin_amdgcn_mfma_f32_16x16x32_bf16(ah1, bh0, acc[1][0], 0, 0, 0);
        acc[1][1] = __builtin_amdgcn_mfma_f32_16x16x32_bf16(ah1, bh1, acc[1][1], 0, 0, 0);
        acc[0][0] = __builtin_amdgcn_mfma_f32_16x16x32_bf16(al0, bh0, acc[0][0], 0, 0, 0);
        acc[0][1] = __builtin_amdgcn_mfma_f32_16x16x32_bf16(al0, bh1, acc[0][1], 0, 0, 0);
        acc[1][0] = __builtin_amdgcn_mfma_f32_16x16x32_bf16(al1, bh0, acc[1][0], 0, 0, 0);
        acc[1][1] = __builtin_amdgcn_mfma_f32_16x16x32_bf16(al1, bh1, acc[1][1], 0, 0, 0);
        acc[0][0] = __builtin_amdgcn_mfma_f32_16x16x32_bf16(ah0, bl0, acc[0][0], 0, 0, 0);
        acc[0][1] = __builtin_amdgcn_mfma_f32_16x16x32_bf16(ah0, bl1, acc[0][1], 0, 0, 0);
        acc[1][0] = __builtin_amdgcn_mfma_f32_16x16x32_bf16(ah1, bl0, acc[1][0], 0, 0, 0);
        acc[1][1] = __builtin_amdgcn_mfma_f32_16x16x32_bf16(ah1, bl1, acc[1][1], 0, 0, 0);
    }

    // epilogue: C/D layout col=lane&15, row=(lane>>4)*4+reg
#pragma unroll
    for (int rt = 0; rt < 2; ++rt) {
#pragma unroll
        for (int ct = 0; ct < 2; ++ct) {
            int colb = wv * 32 + ct * 16 + lr;
#pragma unroll
            for (int e = 0; e < 4; ++e) {
                int row = row0 + rt * 16 + g * 4 + e;
                hb[(size_t)row * D + colb] = f2bf(acc[rt][ct][e]);
            }
        }
    }
}

// ---------------- gather: out[n] = prelu( sum coef*h[src] + dis^2*h[n] + b ) ----------------
__global__ __launch_bounds__(256) void k_gather(
    const int* __restrict__ rowptr, const int2* __restrict__ edges,
    const ushort* __restrict__ hb, const float* __restrict__ dis,
    const float* __restrict__ b, const float* __restrict__ alpha,
    float* __restrict__ out)
{
    int gid = blockIdx.x * 256 + threadIdx.x;
    int n = gid >> 6;
    if (n >= N_NODES) return;
    int lane = gid & 63;
    int q = lane >> 4;           // edge slot 0..3
    int c0 = (lane & 15) * 8;    // 8 cols per lane

    int beg = rowptr[n], end = rowptr[n + 1];
    float acc[8] = {0.f, 0.f, 0.f, 0.f, 0.f, 0.f, 0.f, 0.f};

    for (int e = beg + q; e < end; e += 4) {
        int2 sc = edges[e];
        float c = __int_as_float(sc.y);
        uint4 hv = *(const uint4*)&hb[(size_t)sc.x * D + c0];
#pragma unroll
        for (int j = 0; j < 4; ++j) {
            uint w = ((const uint*)&hv)[j];
            float lo = __uint_as_float(w << 16);
            float hi = __uint_as_float(w & 0xffff0000u);
            acc[2 * j]     = fmaf(c, lo, acc[2 * j]);
            acc[2 * j + 1] = fmaf(c, hi, acc[2 * j + 1]);
        }
    }

#pragma unroll
    for (int j = 0; j < 8; ++j) {
        acc[j] += __shfl_xor(acc[j], 16);
        acc[j] += __shfl_xor(acc[j], 32);
    }

    if (q == 0) {
        float di = dis[n];
        float d2 = di * di;
        uint4 hv = *(const uint4*)&hb[(size_t)n * D + c0];
        float r[8];
#pragma unroll
        for (int j = 0; j < 4; ++j) {
            uint w = ((const uint*)&hv)[j];
            float lo = __uint_as_float(w << 16);
            float hi = __uint_as_float(w & 0xffff0000u);
            r[2 * j]     = acc[2 * j]     + d2 * lo + b[c0 + 2 * j];
            r[2 * j + 1] = acc[2 * j + 1] + d2 * hi + b[c0 + 2 * j + 1];
        }
#pragma unroll
        for (int j = 0; j < 8; ++j) {
            float av = alpha[c0 + j];
            r[j] = r[j] >= 0.f ? r[j] : av * r[j];
        }
        *(float4*)&out[(size_t)n * D + c0]     = make_float4(r[0], r[1], r[2], r[3]);
        *(float4*)&out[(size_t)n * D + c0 + 4] = make_float4(r[4], r[5], r[6], r[7]);
    }
}

// ---------------- launch ----------------

extern "C" void kernel_launch(void* const* d_in, const int* in_sizes, int n_in,
                              void* d_out, int out_size, void* d_ws, size_t ws_size,
                              hipStream_t stream) {
    const float* x   = (const float*)d_in[0];
    const int*   ei  = (const int*)d_in[1];
    const float* ew  = (const float*)d_in[2];
    const float* W1  = (const float*)d_in[3];
    const float* b1  = (const float*)d_in[4];
    const float* a1  = (const float*)d_in[5];
    const float* W2  = (const float*)d_in[6];
    const float* b2  = (const float*)d_in[7];
    const float* a2  = (const float*)d_in[8];
    const float* W3  = (const float*)d_in[9];
    const float* b3  = (const float*)d_in[10];
    const float* a3  = (const float*)d_in[11];

    const int* src = ei;
    const int* dst = ei + N_EDGES;

    float* out = (float*)d_out;

    // workspace layout (8-byte alignment maintained)
    ushort* hb         = (ushort*)d_ws;                          // N*D bf16 (25.6 MB)
    int2*   edges      = (int2*)(hb + (size_t)N_NODES * D);      // E int2 (12.8 MB)
    u64*    packed     = (u64*)(edges + N_EDGES);                // N u64 (800 KB)
    float*  dis        = (float*)(packed + N_NODES);             // N floats
    int*    rowptr     = (int*)(dis + N_NODES);                  // N+1
    int*    rowptr_mut = rowptr + N_NODES + 1;                   // N+1
    int*    bsum       = rowptr_mut + N_NODES + 1;               // 128
    ushort* wsp        = (ushort*)(bsum + 128);                  // 6 x 16384 ushorts
    ushort* Wht1 = wsp;              ushort* Wlt1 = wsp + 16384;
    ushort* Wht2 = wsp + 2 * 16384;  ushort* Wlt2 = wsp + 3 * 16384;
    ushort* Wht3 = wsp + 4 * 16384;  ushort* Wlt3 = wsp + 5 * 16384;

    const int nb_scan = (N_NODES + 1023) / 1024;  // 98

    // W splits (independent of everything else)
    k_wsplit<<<64, 256, 0, stream>>>(W1, Wht1, Wlt1);
    k_wsplit<<<64, 256, 0, stream>>>(W2, Wht2, Wlt2);
    k_wsplit<<<64, 256, 0, stream>>>(W3, Wht3, Wlt3);

    // CSR build
    k_zero_i<<<(2 * N_NODES + 255) / 256, 256, 0, stream>>>((int*)packed, 2 * N_NODES);
    k_pack<<<(N_EDGES + 255) / 256, 256, 0, stream>>>(dst, ew, packed);
    k_scan1<<<nb_scan, 256, 0, stream>>>(packed, dis, rowptr, bsum);
    k_scan2<<<1, 1, 0, stream>>>(bsum, nb_scan);
    k_scan3<<<(N_NODES + 256) / 256, 256, 0, stream>>>(rowptr, rowptr_mut, bsum);
    k_scatter<<<(N_EDGES + 255) / 256, 256, 0, stream>>>(src, dst, ew, dis, rowptr_mut, edges);

    const int gemm_blocks   = N_NODES / TILE_ROWS;   // 3125
    const int gather_blocks = (N_NODES * 64) / 256;  // 25000

    // ----- layer 1 -----
    k_gemm_mfma<<<gemm_blocks, 256, 0, stream>>>(x, Wht1, Wlt1, hb);
    k_gather<<<gather_blocks, 256, 0, stream>>>(rowptr, edges, hb, dis, b1, a1, out);
    // ----- layer 2 -----
    k_gemm_mfma<<<gemm_blocks, 256, 0, stream>>>(out, Wht2, Wlt2, hb);
    k_gather<<<gather_blocks, 256, 0, stream>>>(rowptr, edges, hb, dis, b2, a2, out);
    // ----- layer 3 -----
    k_gemm_mfma<<<gemm_blocks, 256, 0, stream>>>(out, Wht3, Wlt3, hb);
    k_gather<<<gather_blocks, 256, 0, stream>>>(rowptr, edges, hb, dis, b3, a3, out);
}

// Round 6
// 526.878 us; speedup vs baseline: 8.0570x; 1.0407x over previous
//
#include <hip/hip_runtime.h>

#define N_NODES 100000
#define N_EDGES 1600000
#define D 128
#define TILE_ROWS 32
#define NGRP 8
#define GRP_NODES ((N_NODES + NGRP - 1) / NGRP)   // 12500
#define CHUNK 4096
#define NCHUNK ((N_EDGES + CHUNK - 1) / CHUNK)    // 391

typedef unsigned int uint;
typedef unsigned long long u64;
typedef short short8 __attribute__((ext_vector_type(8)));
typedef float f32x4 __attribute__((ext_vector_type(4)));

__device__ inline ushort f2bf(float f) {  // RTNE bf16 (finite inputs)
    union { float f; uint u; } v; v.f = f;
    uint r = v.u + 0x7fffu + ((v.u >> 16) & 1u);
    return (ushort)(r >> 16);
}
__device__ inline float bf2f(ushort b) {
    union { uint u; float f; } v; v.u = ((uint)b) << 16;
    return v.f;
}

// ---------------- utility ----------------

__global__ void k_zero_i(int* __restrict__ p, int n) {
    int i = blockIdx.x * blockDim.x + threadIdx.x;
    if (i < n) p[i] = 0;
}

// packed per-node accumulator: bits [63:40] = in-degree count, [39:0] = sum(ew) in Q31
// XCD-partitioned: group g (blockIdx&7 -> XCD g) handles dst in [g*GRP, (g+1)*GRP)
// so atomics stay in that XCD's L2 (packed slice ~100 KB).
__global__ __launch_bounds__(256) void k_pack8(const int* __restrict__ dst,
                                               const float* __restrict__ ew,
                                               u64* __restrict__ packed) {
    int g = blockIdx.x & 7;
    int chunk = blockIdx.x >> 3;
    int lo = g * GRP_NODES;
    int hi = lo + GRP_NODES;
    int base = chunk * CHUNK;
    for (int k = threadIdx.x; k < CHUNK; k += 256) {
        int e = base + k;
        if (e >= N_EDGES) break;
        int t = dst[e];
        if (t >= lo && t < hi) {
            u64 v = (1ULL << 40) | (u64)llrintf(ew[e] * 2147483648.0f);
            atomicAdd(&packed[t], v);
        }
    }
}

// ---------------- W split: fp32 W[k][c] -> bf16 hi/lo, transposed + swizzled ----------------
__global__ void k_wsplit(const float* __restrict__ W, ushort* __restrict__ Wht,
                         ushort* __restrict__ Wlt) {
    int i = blockIdx.x * 256 + threadIdx.x;   // 16384
    int k = i >> 7, c = i & 127;
    float w = W[i];
    ushort wh = f2bf(w);
    ushort wl = f2bf(w - bf2f(wh));
    int j = k >> 3;
    int off = c * 128 + (((j ^ (c & 7)) << 3) | (k & 7));
    Wht[off] = wh;
    Wlt[off] = wl;
}

// ---------------- scan1: unpack (deg->dis, cnt) + block-local exclusive scan ----------------
__global__ __launch_bounds__(256) void k_scan1(const u64* __restrict__ packed,
                                               float* __restrict__ dis,
                                               int* __restrict__ rowptr,
                                               int* __restrict__ bsum) {
    __shared__ int sd[256];
    int t = threadIdx.x;
    int base = blockIdx.x * 1024 + t * 4;
    int v[4];
#pragma unroll
    for (int j = 0; j < 4; ++j) {
        int idx = base + j;
        int c = 0;
        if (idx < N_NODES) {
            u64 p = packed[idx];
            c = (int)(p >> 40);
            float deg = (float)((double)(p & 0xFFFFFFFFFFULL) * (1.0 / 2147483648.0));
            dis[idx] = rsqrtf(deg + 1.0f);   // self-loop weight 1
        }
        v[j] = c;
    }
    int lsum = v[0] + v[1] + v[2] + v[3];
    sd[t] = lsum;
    __syncthreads();
    for (int off = 1; off < 256; off <<= 1) {
        int x = (t >= off) ? sd[t - off] : 0;
        __syncthreads();
        sd[t] += x;
        __syncthreads();
    }
    int excl = sd[t] - lsum;
    if (base + 0 < N_NODES) rowptr[base + 0] = excl;
    if (base + 1 < N_NODES) rowptr[base + 1] = excl + v[0];
    if (base + 2 < N_NODES) rowptr[base + 2] = excl + v[0] + v[1];
    if (base + 3 < N_NODES) rowptr[base + 3] = excl + v[0] + v[1] + v[2];
    if (t == 255) bsum[blockIdx.x] = sd[255];
}

__global__ void k_scan2(int* __restrict__ bsum, int nb) {
    if (blockIdx.x == 0 && threadIdx.x == 0) {
        int total = 0;
        for (int b = 0; b < nb; ++b) { int x = bsum[b]; bsum[b] = total; total += x; }
    }
}

__global__ void k_scan3(int* __restrict__ rowptr, int* __restrict__ rowptr_mut,
                        const int* __restrict__ bsum) {
    int i = blockIdx.x * blockDim.x + threadIdx.x;
    if (i < N_NODES) {
        int v = rowptr[i] + bsum[i >> 10];
        rowptr[i] = v;
        rowptr_mut[i] = v;
    } else if (i == N_NODES) {
        rowptr[N_NODES] = N_EDGES;
    }
}

// ---------------- scatter edges into CSR buckets (XCD-partitioned) ----------------
// Group g writes only its CSR window (~1.6 MB) + its rowptr_mut slice -> L2-local.
__global__ __launch_bounds__(256) void k_scatter8(const int* __restrict__ src,
                                                  const int* __restrict__ dst,
                                                  const float* __restrict__ ew,
                                                  const float* __restrict__ dis,
                                                  int* __restrict__ rowptr_mut,
                                                  int2* __restrict__ edges) {
    int g = blockIdx.x & 7;
    int chunk = blockIdx.x >> 3;
    int lo = g * GRP_NODES;
    int hi = lo + GRP_NODES;
    int base = chunk * CHUNK;
    for (int k = threadIdx.x; k < CHUNK; k += 256) {
        int e = base + k;
        if (e >= N_EDGES) break;
        int t = dst[e];
        if (t >= lo && t < hi) {
            int s = src[e];
            int pos = atomicAdd(&rowptr_mut[t], 1);
            float coef = dis[s] * ew[e] * dis[t];
            edges[pos] = make_int2(s, __float_as_int(coef));
        }
    }
}

// ---------------- MFMA GEMM: h(bf16) = x(fp32) @ W via 3-term bf16 split ----------------
__global__ __launch_bounds__(256) void k_gemm_mfma(
    const float* __restrict__ x, const ushort* __restrict__ Wht,
    const ushort* __restrict__ Wlt, ushort* __restrict__ hb)
{
    __shared__ ushort WH[16384];   // 32 KB
    __shared__ ushort WL[16384];   // 32 KB
    __shared__ ushort XH[4096];    // 8 KB
    __shared__ ushort XL[4096];    // 8 KB

    const int tx = threadIdx.x;
    const int row0 = blockIdx.x * TILE_ROWS;

    for (int i = tx; i < 2048; i += 256) {
        ((uint4*)WH)[i] = ((const uint4*)Wht)[i];
        ((uint4*)WL)[i] = ((const uint4*)Wlt)[i];
    }

    {
        int m = tx * 2;
        int r = m >> 4;
        int jb = m & 15;
        const float* xp = x + (size_t)(row0 + r) * D;
#pragma unroll
        for (int c = 0; c < 2; ++c) {
            int j = jb + c;
            float4 a0 = *(const float4*)(xp + j * 8);
            float4 a1 = *(const float4*)(xp + j * 8 + 4);
            float v[8] = {a0.x, a0.y, a0.z, a0.w, a1.x, a1.y, a1.z, a1.w};
            uint4 uh, ul;
            uint* ph = (uint*)&uh; uint* pl = (uint*)&ul;
#pragma unroll
            for (int e = 0; e < 4; ++e) {
                ushort h0 = f2bf(v[2 * e]),     h1 = f2bf(v[2 * e + 1]);
                ushort l0 = f2bf(v[2 * e] - bf2f(h0));
                ushort l1 = f2bf(v[2 * e + 1] - bf2f(h1));
                ph[e] = (uint)h0 | ((uint)h1 << 16);
                pl[e] = (uint)l0 | ((uint)l1 << 16);
            }
            int off = r * 16 + (j ^ (r & 7));
            ((uint4*)XH)[off] = uh;
            ((uint4*)XL)[off] = ul;
        }
    }
    __syncthreads();

    const int wv = tx >> 6;
    const int lane = tx & 63;
    const int lr = lane & 15;
    const int g = lane >> 4;

    f32x4 acc[2][2] = {};

    const int c0 = wv * 32 + lr;
    const int c1 = c0 + 16;

#pragma unroll
    for (int ks = 0; ks < 4; ++ks) {
        int co = ((ks * 4 + g) ^ (lr & 7)) << 3;
        short8 ah0 = *(short8*)&XH[lr * 128 + co];
        short8 ah1 = *(short8*)&XH[(16 + lr) * 128 + co];
        short8 al0 = *(short8*)&XL[lr * 128 + co];
        short8 al1 = *(short8*)&XL[(16 + lr) * 128 + co];
        short8 bh0 = *(short8*)&WH[c0 * 128 + co];
        short8 bh1 = *(short8*)&WH[c1 * 128 + co];
        short8 bl0 = *(short8*)&WL[c0 * 128 + co];
        short8 bl1 = *(short8*)&WL[c1 * 128 + co];

        acc[0][0] = __builtin_amdgcn_mfma_f32_16x16x32_bf16(ah0, bh0, acc[0][0], 0, 0, 0);
        acc[0][1] = __builtin_amdgcn_mfma_f32_16x16x32_bf16(ah0, bh1, acc[0][1], 0, 0, 0);
        acc[1][0] = __builtin_amdgcn_mfma_f32_16x16x32_bf16(ah1, bh0, acc[1][0], 0, 0, 0);
        acc[1][1] = __builtin_amdgcn_mfma_f32_16x16x32_bf16(ah1, bh1, acc[1][1], 0, 0, 0);
        acc[0][0] = __builtin_amdgcn_mfma_f32_16x16x32_bf16(al0, bh0, acc[0][0], 0, 0, 0);
        acc[0][1] = __builtin_amdgcn_mfma_f32_16x16x32_bf16(al0, bh1, acc[0][1], 0, 0, 0);
        acc[1][0] = __builtin_amdgcn_mfma_f32_16x16x32_bf16(al1, bh0, acc[1][0], 0, 0, 0);
        acc[1][1] = __builtin_amdgcn_mfma_f32_16x16x32_bf16(al1, bh1, acc[1][1], 0, 0, 0);
        acc[0][0] = __builtin_amdgcn_mfma_f32_16x16x32_bf16(ah0, bl0, acc[0][0], 0, 0, 0);
        acc[0][1] = __builtin_amdgcn_mfma_f32_16x16x32_bf16(ah0, bl1, acc[0][1], 0, 0, 0);
        acc[1][0] = __builtin_amdgcn_mfma_f32_16x16x32_bf16(ah1, bl0, acc[1][0], 0, 0, 0);
        acc[1][1] = __builtin_amdgcn_mfma_f32_16x16x32_bf16(ah1, bl1, acc[1][1], 0, 0, 0);
    }

#pragma unroll
    for (int rt = 0; rt < 2; ++rt) {
#pragma unroll
        for (int ct = 0; ct < 2; ++ct) {
            int colb = wv * 32 + ct * 16 + lr;
#pragma unroll
            for (int e = 0; e < 4; ++e) {
                int row = row0 + rt * 16 + g * 4 + e;
                hb[(size_t)row * D + colb] = f2bf(acc[rt][ct][e]);
            }
        }
    }
}

// ---------------- gather: out[n] = prelu( sum coef*h[src] + dis^2*h[n] + b ) ----------------
// one wave per node; 4 slots x 2-deep unroll = 8 edges in flight.
__global__ __launch_bounds__(256) void k_gather(
    const int* __restrict__ rowptr, const int2* __restrict__ edges,
    const ushort* __restrict__ hb, const float* __restrict__ dis,
    const float* __restrict__ b, const float* __restrict__ alpha,
    float* __restrict__ out)
{
    int gid = blockIdx.x * 256 + threadIdx.x;
    int n = gid >> 6;
    if (n >= N_NODES) return;
    int lane = gid & 63;
    int q = lane >> 4;           // edge slot 0..3
    int c0 = (lane & 15) * 8;    // 8 cols per lane

    int beg = rowptr[n], end = rowptr[n + 1];
    float acc[8] = {0.f, 0.f, 0.f, 0.f, 0.f, 0.f, 0.f, 0.f};

    int e = beg + q;
    for (; e + 4 < end; e += 8) {
        int2 sc0 = edges[e];
        int2 sc1 = edges[e + 4];
        uint4 hv0 = *(const uint4*)&hb[(size_t)sc0.x * D + c0];
        uint4 hv1 = *(const uint4*)&hb[(size_t)sc1.x * D + c0];
        float ca = __int_as_float(sc0.y);
        float cb = __int_as_float(sc1.y);
#pragma unroll
        for (int j = 0; j < 4; ++j) {
            uint w0 = ((const uint*)&hv0)[j];
            uint w1 = ((const uint*)&hv1)[j];
            acc[2 * j]     = fmaf(ca, __uint_as_float(w0 << 16),        acc[2 * j]);
            acc[2 * j + 1] = fmaf(ca, __uint_as_float(w0 & 0xffff0000u), acc[2 * j + 1]);
            acc[2 * j]     = fmaf(cb, __uint_as_float(w1 << 16),        acc[2 * j]);
            acc[2 * j + 1] = fmaf(cb, __uint_as_float(w1 & 0xffff0000u), acc[2 * j + 1]);
        }
    }
    if (e < end) {
        int2 sc = edges[e];
        float c = __int_as_float(sc.y);
        uint4 hv = *(const uint4*)&hb[(size_t)sc.x * D + c0];
#pragma unroll
        for (int j = 0; j < 4; ++j) {
            uint w = ((const uint*)&hv)[j];
            acc[2 * j]     = fmaf(c, __uint_as_float(w << 16),        acc[2 * j]);
            acc[2 * j + 1] = fmaf(c, __uint_as_float(w & 0xffff0000u), acc[2 * j + 1]);
        }
    }

#pragma unroll
    for (int j = 0; j < 8; ++j) {
        acc[j] += __shfl_xor(acc[j], 16);
        acc[j] += __shfl_xor(acc[j], 32);
    }

    if (q == 0) {
        float di = dis[n];
        float d2 = di * di;
        uint4 hv = *(const uint4*)&hb[(size_t)n * D + c0];
        float r[8];
#pragma unroll
        for (int j = 0; j < 4; ++j) {
            uint w = ((const uint*)&hv)[j];
            float lo = __uint_as_float(w << 16);
            float hi = __uint_as_float(w & 0xffff0000u);
            r[2 * j]     = acc[2 * j]     + d2 * lo + b[c0 + 2 * j];
            r[2 * j + 1] = acc[2 * j + 1] + d2 * hi + b[c0 + 2 * j + 1];
        }
#pragma unroll
        for (int j = 0; j < 8; ++j) {
            float av = alpha[c0 + j];
            r[j] = r[j] >= 0.f ? r[j] : av * r[j];
        }
        *(float4*)&out[(size_t)n * D + c0]     = make_float4(r[0], r[1], r[2], r[3]);
        *(float4*)&out[(size_t)n * D + c0 + 4] = make_float4(r[4], r[5], r[6], r[7]);
    }
}

// ---------------- launch ----------------

extern "C" void kernel_launch(void* const* d_in, const int* in_sizes, int n_in,
                              void* d_out, int out_size, void* d_ws, size_t ws_size,
                              hipStream_t stream) {
    const float* x   = (const float*)d_in[0];
    const int*   ei  = (const int*)d_in[1];
    const float* ew  = (const float*)d_in[2];
    const float* W1  = (const float*)d_in[3];
    const float* b1  = (const float*)d_in[4];
    const float* a1  = (const float*)d_in[5];
    const float* W2  = (const float*)d_in[6];
    const float* b2  = (const float*)d_in[7];
    const float* a2  = (const float*)d_in[8];
    const float* W3  = (const float*)d_in[9];
    const float* b3  = (const float*)d_in[10];
    const float* a3  = (const float*)d_in[11];

    const int* src = ei;
    const int* dst = ei + N_EDGES;

    float* out = (float*)d_out;

    // workspace layout (8-byte alignment maintained)
    ushort* hb         = (ushort*)d_ws;                          // N*D bf16 (25.6 MB)
    int2*   edges      = (int2*)(hb + (size_t)N_NODES * D);      // E int2 (12.8 MB)
    u64*    packed     = (u64*)(edges + N_EDGES);                // N u64 (800 KB)
    float*  dis        = (float*)(packed + N_NODES);             // N floats
    int*    rowptr     = (int*)(dis + N_NODES);                  // N+1
    int*    rowptr_mut = rowptr + N_NODES + 1;                   // N+1
    int*    bsum       = rowptr_mut + N_NODES + 1;               // 128
    ushort* wsp        = (ushort*)(bsum + 128);                  // 6 x 16384 ushorts
    ushort* Wht1 = wsp;              ushort* Wlt1 = wsp + 16384;
    ushort* Wht2 = wsp + 2 * 16384;  ushort* Wlt2 = wsp + 3 * 16384;
    ushort* Wht3 = wsp + 4 * 16384;  ushort* Wlt3 = wsp + 5 * 16384;

    const int nb_scan = (N_NODES + 1023) / 1024;  // 98

    // W splits (independent of everything else)
    k_wsplit<<<64, 256, 0, stream>>>(W1, Wht1, Wlt1);
    k_wsplit<<<64, 256, 0, stream>>>(W2, Wht2, Wlt2);
    k_wsplit<<<64, 256, 0, stream>>>(W3, Wht3, Wlt3);

    // CSR build (XCD-partitioned pack/scatter)
    k_zero_i<<<(2 * N_NODES + 255) / 256, 256, 0, stream>>>((int*)packed, 2 * N_NODES);
    k_pack8<<<NGRP * NCHUNK, 256, 0, stream>>>(dst, ew, packed);
    k_scan1<<<nb_scan, 256, 0, stream>>>(packed, dis, rowptr, bsum);
    k_scan2<<<1, 1, 0, stream>>>(bsum, nb_scan);
    k_scan3<<<(N_NODES + 256) / 256, 256, 0, stream>>>(rowptr, rowptr_mut, bsum);
    k_scatter8<<<NGRP * NCHUNK, 256, 0, stream>>>(src, dst, ew, dis, rowptr_mut, edges);

    const int gemm_blocks   = N_NODES / TILE_ROWS;   // 3125
    const int gather_blocks = (N_NODES * 64) / 256;  // 25000

    // ----- layer 1 -----
    k_gemm_mfma<<<gemm_blocks, 256, 0, stream>>>(x, Wht1, Wlt1, hb);
    k_gather<<<gather_blocks, 256, 0, stream>>>(rowptr, edges, hb, dis, b1, a1, out);
    // ----- layer 2 -----
    k_gemm_mfma<<<gemm_blocks, 256, 0, stream>>>(out, Wht2, Wlt2, hb);
    k_gather<<<gather_blocks, 256, 0, stream>>>(rowptr, edges, hb, dis, b2, a2, out);
    // ----- layer 3 -----
    k_gemm_mfma<<<gemm_blocks, 256, 0, stream>>>(out, Wht3, Wlt3, hb);
    k_gather<<<gather_blocks, 256, 0, stream>>>(rowptr, edges, hb, dis, b3, a3, out);
}

// Round 7
// 415.948 us; speedup vs baseline: 10.2057x; 1.2667x over previous
//
#include <hip/hip_runtime.h>

#define N_NODES 100000
#define N_EDGES 1600000
#define D 128
#define TILE_ROWS 32
#define CHUNK 4096
#define NC ((N_EDGES + CHUNK - 1) / CHUNK)   // 391 chunks
#define NB ((N_NODES + 255) / 256)           // 391 buckets (256 nodes each)
#define HLEN (NB * NC)                       // 152881
#define SCAN_BLK ((HLEN + 1023) / 1024)      // 150

typedef unsigned int uint;
typedef unsigned long long u64;
typedef short short8 __attribute__((ext_vector_type(8)));
typedef float f32x4 __attribute__((ext_vector_type(4)));

__device__ inline ushort f2bf(float f) {  // RTNE bf16 (finite inputs)
    union { float f; uint u; } v; v.f = f;
    uint r = v.u + 0x7fffu + ((v.u >> 16) & 1u);
    return (ushort)(r >> 16);
}
__device__ inline float bf2f(ushort b) {
    union { uint u; float f; } v; v.u = ((uint)b) << 16;
    return v.f;
}

// ================= CSR build: two-level bucket sort, no global atomics =================

// Stage 1: per-chunk histogram over dst>>8. H is chunk-major: H[c*NB + b].
__global__ __launch_bounds__(256) void k_hist(const int* __restrict__ dst, int* __restrict__ H) {
    __shared__ int hist[NB];
    int c = blockIdx.x;
    for (int i = threadIdx.x; i < NB; i += 256) hist[i] = 0;
    __syncthreads();
    int base = c * CHUNK;
    int lim = N_EDGES - base; if (lim > CHUNK) lim = CHUNK;
    for (int k = threadIdx.x; k < lim; k += 256)
        atomicAdd(&hist[dst[base + k] >> 8], 1);
    __syncthreads();
    for (int i = threadIdx.x; i < NB; i += 256) H[c * NB + i] = hist[i];
}

// Stage 2: exclusive scan of H in bucket-major logical order l = b*NC + c.
__global__ __launch_bounds__(256) void k_scanA(const int* __restrict__ H, int* __restrict__ HOFF,
                                               int* __restrict__ bsum) {
    __shared__ int sd[256];
    int t = threadIdx.x;
    int base = blockIdx.x * 1024 + t * 4;
    int v[4];
#pragma unroll
    for (int j = 0; j < 4; ++j) {
        int l = base + j;
        v[j] = (l < HLEN) ? H[(l % NC) * NB + (l / NC)] : 0;   // transposed read
    }
    int lsum = v[0] + v[1] + v[2] + v[3];
    sd[t] = lsum;
    __syncthreads();
    for (int off = 1; off < 256; off <<= 1) {
        int x = (t >= off) ? sd[t - off] : 0;
        __syncthreads();
        sd[t] += x;
        __syncthreads();
    }
    int excl = sd[t] - lsum;
    if (base + 0 < HLEN) HOFF[base + 0] = excl;
    if (base + 1 < HLEN) HOFF[base + 1] = excl + v[0];
    if (base + 2 < HLEN) HOFF[base + 2] = excl + v[0] + v[1];
    if (base + 3 < HLEN) HOFF[base + 3] = excl + v[0] + v[1] + v[2];
    if (t == 255) bsum[blockIdx.x] = sd[255];
}

__global__ void k_scanB(int* __restrict__ bsum) {
    if (blockIdx.x == 0 && threadIdx.x == 0) {
        int total = 0;
        for (int b = 0; b < SCAN_BLK; ++b) { int x = bsum[b]; bsum[b] = total; total += x; }
    }
}

__global__ void k_scanC(int* __restrict__ HOFF, const int* __restrict__ bsum) {
    int i = blockIdx.x * blockDim.x + threadIdx.x;
    if (i < HLEN) HOFF[i] += bsum[i >> 10];
}

// Stage 3: scatter u64 records (src | dst<<17 | Q30(ew)<<34) into bucket-major tmp.
// Each block writes 391 short sequential runs -> L2-resident full lines.
__global__ __launch_bounds__(256) void k_pscat(const int* __restrict__ src, const int* __restrict__ dst,
                                               const float* __restrict__ ew, const int* __restrict__ HOFF,
                                               u64* __restrict__ tmp) {
    __shared__ int cur[NB];
    int c = blockIdx.x;
    for (int i = threadIdx.x; i < NB; i += 256) cur[i] = HOFF[i * NC + c];
    __syncthreads();
    int base = c * CHUNK;
    int lim = N_EDGES - base; if (lim > CHUNK) lim = CHUNK;
    for (int k = threadIdx.x; k < lim; k += 256) {
        int e = base + k;
        int s = src[e], t = dst[e];
        u64 q = (u64)llrintf(ew[e] * 1073741824.0f);   // Q30, ew in [0,1)
        int pos = atomicAdd(&cur[t >> 8], 1);
        tmp[pos] = (u64)s | ((u64)t << 17) | (q << 34);
    }
}

// Stage B1: one block per bucket: per-node counts + weighted degree (LDS),
// emit rowptr (exclusive scan) and dis = rsqrt(deg+1). Replaces pack+node-scan.
__global__ __launch_bounds__(256) void k_b1(const int* __restrict__ HOFF, const u64* __restrict__ tmp,
                                            float* __restrict__ dis, int* __restrict__ rowptr) {
    __shared__ int cnt[256];
    __shared__ u64 degq[256];
    __shared__ int sd[256];
    __shared__ int sbeg, send;
    int b = blockIdx.x, t = threadIdx.x;
    cnt[t] = 0; degq[t] = 0;
    if (t == 0) {
        sbeg = HOFF[b * NC];
        send = (b + 1 < NB) ? HOFF[(b + 1) * NC] : N_EDGES;
    }
    __syncthreads();
    int beg = sbeg, end = send, lo = b << 8;
    for (int e = beg + t; e < end; e += 256) {
        u64 r = tmp[e];
        int loc = (int)((r >> 17) & 0x1FFFF) - lo;
        atomicAdd(&cnt[loc], 1);
        atomicAdd(&degq[loc], r >> 34);
    }
    __syncthreads();
    int n = lo + t;
    if (n < N_NODES) {
        float deg = (float)((double)degq[t] * (1.0 / 1073741824.0));
        dis[n] = rsqrtf(deg + 1.0f);   // self-loop weight 1
    }
    int v = cnt[t];
    sd[t] = v;
    __syncthreads();
    for (int off = 1; off < 256; off <<= 1) {
        int x = (t >= off) ? sd[t - off] : 0;
        __syncthreads();
        sd[t] += x;
        __syncthreads();
    }
    if (n < N_NODES) rowptr[n] = beg + sd[t] - v;
    if (b == NB - 1 && t == 0) rowptr[N_NODES] = N_EDGES;
}

// Stage B2: one block per bucket: final scatter within the bucket's own CSR
// window (~32 KB, single block -> single L2 -> full-line writebacks).
__global__ __launch_bounds__(256) void k_b2(const int* __restrict__ HOFF, const u64* __restrict__ tmp,
                                            const float* __restrict__ dis, const int* __restrict__ rowptr,
                                            int2* __restrict__ edges) {
    __shared__ int cur[256];
    __shared__ float disl[256];
    __shared__ int sbeg, send;
    int b = blockIdx.x, t = threadIdx.x;
    int lo = b << 8;
    int n = lo + t;
    cur[t] = (n < N_NODES) ? rowptr[n] : 0;
    disl[t] = (n < N_NODES) ? dis[n] : 0.0f;
    if (t == 0) {
        sbeg = HOFF[b * NC];
        send = (b + 1 < NB) ? HOFF[(b + 1) * NC] : N_EDGES;
    }
    __syncthreads();
    for (int e = sbeg + t; e < send; e += 256) {
        u64 r = tmp[e];
        int s = (int)(r & 0x1FFFF);
        int loc = (int)((r >> 17) & 0x1FFFF) - lo;
        float w = (float)(r >> 34) * (1.0f / 1073741824.0f);
        float coef = dis[s] * w * disl[loc];
        int pos = atomicAdd(&cur[loc], 1);
        edges[pos] = make_int2(s, __float_as_int(coef));
    }
}

// ---------------- W split: fp32 W[k][c] -> bf16 hi/lo, transposed + swizzled ----------------
__global__ void k_wsplit(const float* __restrict__ W, ushort* __restrict__ Wht,
                         ushort* __restrict__ Wlt) {
    int i = blockIdx.x * 256 + threadIdx.x;   // 16384
    int k = i >> 7, c = i & 127;
    float w = W[i];
    ushort wh = f2bf(w);
    ushort wl = f2bf(w - bf2f(wh));
    int j = k >> 3;
    int off = c * 128 + (((j ^ (c & 7)) << 3) | (k & 7));
    Wht[off] = wh;
    Wlt[off] = wl;
}

// ---------------- MFMA GEMM: h(bf16) = x(fp32) @ W via 3-term bf16 split ----------------
__global__ __launch_bounds__(256) void k_gemm_mfma(
    const float* __restrict__ x, const ushort* __restrict__ Wht,
    const ushort* __restrict__ Wlt, ushort* __restrict__ hb)
{
    __shared__ ushort WH[16384];   // 32 KB
    __shared__ ushort WL[16384];   // 32 KB
    __shared__ ushort XH[4096];    // 8 KB
    __shared__ ushort XL[4096];    // 8 KB

    const int tx = threadIdx.x;
    const int row0 = blockIdx.x * TILE_ROWS;

    for (int i = tx; i < 2048; i += 256) {
        ((uint4*)WH)[i] = ((const uint4*)Wht)[i];
        ((uint4*)WL)[i] = ((const uint4*)Wlt)[i];
    }

    {
        int m = tx * 2;
        int r = m >> 4;
        int jb = m & 15;
        const float* xp = x + (size_t)(row0 + r) * D;
#pragma unroll
        for (int c = 0; c < 2; ++c) {
            int j = jb + c;
            float4 a0 = *(const float4*)(xp + j * 8);
            float4 a1 = *(const float4*)(xp + j * 8 + 4);
            float v[8] = {a0.x, a0.y, a0.z, a0.w, a1.x, a1.y, a1.z, a1.w};
            uint4 uh, ul;
            uint* ph = (uint*)&uh; uint* pl = (uint*)&ul;
#pragma unroll
            for (int e = 0; e < 4; ++e) {
                ushort h0 = f2bf(v[2 * e]),     h1 = f2bf(v[2 * e + 1]);
                ushort l0 = f2bf(v[2 * e] - bf2f(h0));
                ushort l1 = f2bf(v[2 * e + 1] - bf2f(h1));
                ph[e] = (uint)h0 | ((uint)h1 << 16);
                pl[e] = (uint)l0 | ((uint)l1 << 16);
            }
            int off = r * 16 + (j ^ (r & 7));
            ((uint4*)XH)[off] = uh;
            ((uint4*)XL)[off] = ul;
        }
    }
    __syncthreads();

    const int wv = tx >> 6;
    const int lane = tx & 63;
    const int lr = lane & 15;
    const int g = lane >> 4;

    f32x4 acc[2][2] = {};

    const int c0 = wv * 32 + lr;
    const int c1 = c0 + 16;

#pragma unroll
    for (int ks = 0; ks < 4; ++ks) {
        int co = ((ks * 4 + g) ^ (lr & 7)) << 3;
        short8 ah0 = *(short8*)&XH[lr * 128 + co];
        short8 ah1 = *(short8*)&XH[(16 + lr) * 128 + co];
        short8 al0 = *(short8*)&XL[lr * 128 + co];
        short8 al1 = *(short8*)&XL[(16 + lr) * 128 + co];
        short8 bh0 = *(short8*)&WH[c0 * 128 + co];
        short8 bh1 = *(short8*)&WH[c1 * 128 + co];
        short8 bl0 = *(short8*)&WL[c0 * 128 + co];
        short8 bl1 = *(short8*)&WL[c1 * 128 + co];

        acc[0][0] = __builtin_amdgcn_mfma_f32_16x16x32_bf16(ah0, bh0, acc[0][0], 0, 0, 0);
        acc[0][1] = __builtin_amdgcn_mfma_f32_16x16x32_bf16(ah0, bh1, acc[0][1], 0, 0, 0);
        acc[1][0] = __builtin_amdgcn_mfma_f32_16x16x32_bf16(ah1, bh0, acc[1][0], 0, 0, 0);
        acc[1][1] = __builtin_amdgcn_mfma_f32_16x16x32_bf16(ah1, bh1, acc[1][1], 0, 0, 0);
        acc[0][0] = __builtin_amdgcn_mfma_f32_16x16x32_bf16(al0, bh0, acc[0][0], 0, 0, 0);
        acc[0][1] = __builtin_amdgcn_mfma_f32_16x16x32_bf16(al0, bh1, acc[0][1], 0, 0, 0);
        acc[1][0] = __builtin_amdgcn_mfma_f32_16x16x32_bf16(al1, bh0, acc[1][0], 0, 0, 0);
        acc[1][1] = __builtin_amdgcn_mfma_f32_16x16x32_bf16(al1, bh1, acc[1][1], 0, 0, 0);
        acc[0][0] = __builtin_amdgcn_mfma_f32_16x16x32_bf16(ah0, bl0, acc[0][0], 0, 0, 0);
        acc[0][1] = __builtin_amdgcn_mfma_f32_16x16x32_bf16(ah0, bl1, acc[0][1], 0, 0, 0);
        acc[1][0] = __builtin_amdgcn_mfma_f32_16x16x32_bf16(ah1, bl0, acc[1][0], 0, 0, 0);
        acc[1][1] = __builtin_amdgcn_mfma_f32_16x16x32_bf16(ah1, bl1, acc[1][1], 0, 0, 0);
    }

#pragma unroll
    for (int rt = 0; rt < 2; ++rt) {
#pragma unroll
        for (int ct = 0; ct < 2; ++ct) {
            int colb = wv * 32 + ct * 16 + lr;
#pragma unroll
            for (int e = 0; e < 4; ++e) {
                int row = row0 + rt * 16 + g * 4 + e;
                hb[(size_t)row * D + colb] = f2bf(acc[rt][ct][e]);
            }
        }
    }
}

// ---------------- gather: out[n] = prelu( sum coef*h[src] + dis^2*h[n] + b ) ----------------
// one wave per node; 4 slots x 4-deep unroll = 16 edges in flight.
__global__ __launch_bounds__(256) void k_gather(
    const int* __restrict__ rowptr, const int2* __restrict__ edges,
    const ushort* __restrict__ hb, const float* __restrict__ dis,
    const float* __restrict__ b, const float* __restrict__ alpha,
    float* __restrict__ out)
{
    int gid = blockIdx.x * 256 + threadIdx.x;
    int n = gid >> 6;
    if (n >= N_NODES) return;
    int lane = gid & 63;
    int q = lane >> 4;           // edge slot 0..3
    int c0 = (lane & 15) * 8;    // 8 cols per lane

    int beg = rowptr[n], end = rowptr[n + 1];
    float acc[8] = {0.f, 0.f, 0.f, 0.f, 0.f, 0.f, 0.f, 0.f};

    int e = beg + q;
    for (; e + 12 < end; e += 16) {
        int2 sc0 = edges[e];
        int2 sc1 = edges[e + 4];
        int2 sc2 = edges[e + 8];
        int2 sc3 = edges[e + 12];
        uint4 hv0 = *(const uint4*)&hb[(size_t)sc0.x * D + c0];
        uint4 hv1 = *(const uint4*)&hb[(size_t)sc1.x * D + c0];
        uint4 hv2 = *(const uint4*)&hb[(size_t)sc2.x * D + c0];
        uint4 hv3 = *(const uint4*)&hb[(size_t)sc3.x * D + c0];
        float ca = __int_as_float(sc0.y);
        float cb = __int_as_float(sc1.y);
        float cc = __int_as_float(sc2.y);
        float cd = __int_as_float(sc3.y);
#pragma unroll
        for (int j = 0; j < 4; ++j) {
            uint w0 = ((const uint*)&hv0)[j];
            uint w1 = ((const uint*)&hv1)[j];
            uint w2 = ((const uint*)&hv2)[j];
            uint w3 = ((const uint*)&hv3)[j];
            acc[2 * j]     = fmaf(ca, __uint_as_float(w0 << 16),         acc[2 * j]);
            acc[2 * j + 1] = fmaf(ca, __uint_as_float(w0 & 0xffff0000u), acc[2 * j + 1]);
            acc[2 * j]     = fmaf(cb, __uint_as_float(w1 << 16),         acc[2 * j]);
            acc[2 * j + 1] = fmaf(cb, __uint_as_float(w1 & 0xffff0000u), acc[2 * j + 1]);
            acc[2 * j]     = fmaf(cc, __uint_as_float(w2 << 16),         acc[2 * j]);
            acc[2 * j + 1] = fmaf(cc, __uint_as_float(w2 & 0xffff0000u), acc[2 * j + 1]);
            acc[2 * j]     = fmaf(cd, __uint_as_float(w3 << 16),         acc[2 * j]);
            acc[2 * j + 1] = fmaf(cd, __uint_as_float(w3 & 0xffff0000u), acc[2 * j + 1]);
        }
    }
    for (; e < end; e += 4) {
        int2 sc = edges[e];
        float c = __int_as_float(sc.y);
        uint4 hv = *(const uint4*)&hb[(size_t)sc.x * D + c0];
#pragma unroll
        for (int j = 0; j < 4; ++j) {
            uint w = ((const uint*)&hv)[j];
            acc[2 * j]     = fmaf(c, __uint_as_float(w << 16),         acc[2 * j]);
            acc[2 * j + 1] = fmaf(c, __uint_as_float(w & 0xffff0000u), acc[2 * j + 1]);
        }
    }

#pragma unroll
    for (int j = 0; j < 8; ++j) {
        acc[j] += __shfl_xor(acc[j], 16);
        acc[j] += __shfl_xor(acc[j], 32);
    }

    if (q == 0) {
        float di = dis[n];
        float d2 = di * di;
        uint4 hv = *(const uint4*)&hb[(size_t)n * D + c0];
        float r[8];
#pragma unroll
        for (int j = 0; j < 4; ++j) {
            uint w = ((const uint*)&hv)[j];
            float lo = __uint_as_float(w << 16);
            float hi = __uint_as_float(w & 0xffff0000u);
            r[2 * j]     = acc[2 * j]     + d2 * lo + b[c0 + 2 * j];
            r[2 * j + 1] = acc[2 * j + 1] + d2 * hi + b[c0 + 2 * j + 1];
        }
#pragma unroll
        for (int j = 0; j < 8; ++j) {
            float av = alpha[c0 + j];
            r[j] = r[j] >= 0.f ? r[j] : av * r[j];
        }
        *(float4*)&out[(size_t)n * D + c0]     = make_float4(r[0], r[1], r[2], r[3]);
        *(float4*)&out[(size_t)n * D + c0 + 4] = make_float4(r[4], r[5], r[6], r[7]);
    }
}

// ---------------- launch ----------------

extern "C" void kernel_launch(void* const* d_in, const int* in_sizes, int n_in,
                              void* d_out, int out_size, void* d_ws, size_t ws_size,
                              hipStream_t stream) {
    const float* x   = (const float*)d_in[0];
    const int*   ei  = (const int*)d_in[1];
    const float* ew  = (const float*)d_in[2];
    const float* W1  = (const float*)d_in[3];
    const float* b1  = (const float*)d_in[4];
    const float* a1  = (const float*)d_in[5];
    const float* W2  = (const float*)d_in[6];
    const float* b2  = (const float*)d_in[7];
    const float* a2  = (const float*)d_in[8];
    const float* W3  = (const float*)d_in[9];
    const float* b3  = (const float*)d_in[10];
    const float* a3  = (const float*)d_in[11];

    const int* src = ei;
    const int* dst = ei + N_EDGES;

    float* out = (float*)d_out;

    // workspace layout (8-byte alignment maintained; ~53.5 MB total)
    ushort* hb    = (ushort*)d_ws;                       // N*D bf16   (25.6 MB)
    int2*   edges = (int2*)(hb + (size_t)N_NODES * D);   // E int2     (12.8 MB)
    u64*    tmp   = (u64*)(edges + N_EDGES);             // E u64      (12.8 MB)
    int*    H     = (int*)(tmp + N_EDGES);               // HLEN       (0.61 MB)
    int*    HOFF  = H + HLEN;                            // HLEN       (0.61 MB)
    int*    bsum  = HOFF + HLEN;                         // 256
    float*  dis   = (float*)(bsum + 256);                // N
    int*    rowptr= (int*)(dis + N_NODES);               // N+1 (+pad to even)
    ushort* wsp   = (ushort*)(rowptr + N_NODES + 2);     // 6 x 16384 ushorts
    ushort* Wht1 = wsp;              ushort* Wlt1 = wsp + 16384;
    ushort* Wht2 = wsp + 2 * 16384;  ushort* Wlt2 = wsp + 3 * 16384;
    ushort* Wht3 = wsp + 4 * 16384;  ushort* Wlt3 = wsp + 5 * 16384;

    // W splits (independent of everything else)
    k_wsplit<<<64, 256, 0, stream>>>(W1, Wht1, Wlt1);
    k_wsplit<<<64, 256, 0, stream>>>(W2, Wht2, Wlt2);
    k_wsplit<<<64, 256, 0, stream>>>(W3, Wht3, Wlt3);

    // CSR build: hist -> scan -> bucket scatter -> per-bucket count/deg -> final scatter
    k_hist<<<NC, 256, 0, stream>>>(dst, H);
    k_scanA<<<SCAN_BLK, 256, 0, stream>>>(H, HOFF, bsum);
    k_scanB<<<1, 1, 0, stream>>>(bsum);
    k_scanC<<<(HLEN + 255) / 256, 256, 0, stream>>>(HOFF, bsum);
    k_pscat<<<NC, 256, 0, stream>>>(src, dst, ew, HOFF, tmp);
    k_b1<<<NB, 256, 0, stream>>>(HOFF, tmp, dis, rowptr);
    k_b2<<<NB, 256, 0, stream>>>(HOFF, tmp, dis, rowptr, edges);

    const int gemm_blocks   = N_NODES / TILE_ROWS;   // 3125
    const int gather_blocks = (N_NODES * 64) / 256;  // 25000

    // ----- layer 1 -----
    k_gemm_mfma<<<gemm_blocks, 256, 0, stream>>>(x, Wht1, Wlt1, hb);
    k_gather<<<gather_blocks, 256, 0, stream>>>(rowptr, edges, hb, dis, b1, a1, out);
    // ----- layer 2 -----
    k_gemm_mfma<<<gemm_blocks, 256, 0, stream>>>(out, Wht2, Wlt2, hb);
    k_gather<<<gather_blocks, 256, 0, stream>>>(rowptr, edges, hb, dis, b2, a2, out);
    // ----- layer 3 -----
    k_gemm_mfma<<<gemm_blocks, 256, 0, stream>>>(out, Wht3, Wlt3, hb);
    k_gather<<<gather_blocks, 256, 0, stream>>>(rowptr, edges, hb, dis, b3, a3, out);
}

// Round 9
// 384.337 us; speedup vs baseline: 11.0451x; 1.0822x over previous
//
#include <hip/hip_runtime.h>

#define N_NODES 100000
#define N_EDGES 1600000
#define D 128
#define TILE_ROWS 32
#define N_TILES (N_NODES / TILE_ROWS)        // 3125
#define GEMM_BLOCKS 512
#define CHUNK 4096
#define NC ((N_EDGES + CHUNK - 1) / CHUNK)   // 391 chunks
#define NB ((N_NODES + 255) / 256)           // 391 buckets (256 nodes each)
#define HLEN (NB * NC)                       // 152881
#define SCAN_BLK ((HLEN + 1023) / 1024)      // 150

typedef unsigned int uint;
typedef unsigned long long u64;
typedef short short8 __attribute__((ext_vector_type(8)));
typedef float f32x4 __attribute__((ext_vector_type(4)));

__device__ inline ushort f2bf(float f) {  // RTNE bf16 (finite inputs)
    union { float f; uint u; } v; v.f = f;
    uint r = v.u + 0x7fffu + ((v.u >> 16) & 1u);
    return (ushort)(r >> 16);
}
__device__ inline float bf2f(ushort b) {
    union { uint u; float f; } v; v.u = ((uint)b) << 16;
    return v.f;
}

// ================= CSR build: two-level bucket sort, no global atomics =================

// Stage 1: per-chunk histogram over dst>>8. H is chunk-major: H[c*NB + b].
__global__ __launch_bounds__(256) void k_hist(const int* __restrict__ dst, int* __restrict__ H) {
    __shared__ int hist[NB];
    int c = blockIdx.x;
    for (int i = threadIdx.x; i < NB; i += 256) hist[i] = 0;
    __syncthreads();
    int base = c * CHUNK;
    int lim = N_EDGES - base; if (lim > CHUNK) lim = CHUNK;
    for (int k = threadIdx.x; k < lim; k += 256)
        atomicAdd(&hist[dst[base + k] >> 8], 1);
    __syncthreads();
    for (int i = threadIdx.x; i < NB; i += 256) H[c * NB + i] = hist[i];
}

// Stage 2: exclusive scan of H in bucket-major logical order l = b*NC + c.
__global__ __launch_bounds__(256) void k_scanA(const int* __restrict__ H, int* __restrict__ HOFF,
                                               int* __restrict__ bsum) {
    __shared__ int sd[256];
    int t = threadIdx.x;
    int base = blockIdx.x * 1024 + t * 4;
    int v[4];
#pragma unroll
    for (int j = 0; j < 4; ++j) {
        int l = base + j;
        v[j] = (l < HLEN) ? H[(l % NC) * NB + (l / NC)] : 0;   // transposed read
    }
    int lsum = v[0] + v[1] + v[2] + v[3];
    sd[t] = lsum;
    __syncthreads();
    for (int off = 1; off < 256; off <<= 1) {
        int x = (t >= off) ? sd[t - off] : 0;
        __syncthreads();
        sd[t] += x;
        __syncthreads();
    }
    int excl = sd[t] - lsum;
    if (base + 0 < HLEN) HOFF[base + 0] = excl;
    if (base + 1 < HLEN) HOFF[base + 1] = excl + v[0];
    if (base + 2 < HLEN) HOFF[base + 2] = excl + v[0] + v[1];
    if (base + 3 < HLEN) HOFF[base + 3] = excl + v[0] + v[1] + v[2];
    if (t == 255) bsum[blockIdx.x] = sd[255];
}

// parallel scan of the 150 block sums
__global__ __launch_bounds__(256) void k_scanB(int* __restrict__ bsum) {
    __shared__ int sd[256];
    int t = threadIdx.x;
    int v = (t < SCAN_BLK) ? bsum[t] : 0;
    sd[t] = v;
    __syncthreads();
    for (int off = 1; off < 256; off <<= 1) {
        int x = (t >= off) ? sd[t - off] : 0;
        __syncthreads();
        sd[t] += x;
        __syncthreads();
    }
    if (t < SCAN_BLK) bsum[t] = sd[t] - v;
}

__global__ void k_scanC(int* __restrict__ HOFF, const int* __restrict__ bsum) {
    int i = blockIdx.x * blockDim.x + threadIdx.x;
    if (i < HLEN) HOFF[i] += bsum[i >> 10];
}

// Stage 3: scatter u64 records (src | dst<<17 | Q30(ew)<<34) into bucket-major tmp.
__global__ __launch_bounds__(256) void k_pscat(const int* __restrict__ src, const int* __restrict__ dst,
                                               const float* __restrict__ ew, const int* __restrict__ HOFF,
                                               u64* __restrict__ tmp) {
    __shared__ int cur[NB];
    int c = blockIdx.x;
    for (int i = threadIdx.x; i < NB; i += 256) cur[i] = HOFF[i * NC + c];
    __syncthreads();
    int base = c * CHUNK;
    int lim = N_EDGES - base; if (lim > CHUNK) lim = CHUNK;
    for (int k = threadIdx.x; k < lim; k += 256) {
        int e = base + k;
        int s = src[e], t = dst[e];
        u64 q = (u64)llrintf(ew[e] * 1073741824.0f);   // Q30, ew in [0,1)
        int pos = atomicAdd(&cur[t >> 8], 1);
        tmp[pos] = (u64)s | ((u64)t << 17) | (q << 34);
    }
}

// Stage B1: one block per bucket: per-node counts + weighted degree (LDS),
// emit rowptr (exclusive scan) and dis = rsqrt(deg+1).
// MUST complete for ALL nodes before B2 (B2 reads dis[s] of other buckets).
__global__ __launch_bounds__(256) void k_b1(const int* __restrict__ HOFF, const u64* __restrict__ tmp,
                                            float* __restrict__ dis, int* __restrict__ rowptr) {
    __shared__ int cnt[256];
    __shared__ u64 degq[256];
    __shared__ int sd[256];
    __shared__ int sbeg, send;
    int b = blockIdx.x, t = threadIdx.x;
    cnt[t] = 0; degq[t] = 0;
    if (t == 0) {
        sbeg = HOFF[b * NC];
        send = (b + 1 < NB) ? HOFF[(b + 1) * NC] : N_EDGES;
    }
    __syncthreads();
    int beg = sbeg, end = send, lo = b << 8;
    for (int e = beg + t; e < end; e += 256) {
        u64 r = tmp[e];
        int loc = (int)((r >> 17) & 0x1FFFF) - lo;
        atomicAdd(&cnt[loc], 1);
        atomicAdd(&degq[loc], r >> 34);
    }
    __syncthreads();
    int n = lo + t;
    if (n < N_NODES) {
        float deg = (float)((double)degq[t] * (1.0 / 1073741824.0));
        dis[n] = rsqrtf(deg + 1.0f);   // self-loop weight 1
    }
    int v = cnt[t];
    sd[t] = v;
    __syncthreads();
    for (int off = 1; off < 256; off <<= 1) {
        int x = (t >= off) ? sd[t - off] : 0;
        __syncthreads();
        sd[t] += x;
        __syncthreads();
    }
    if (n < N_NODES) rowptr[n] = beg + sd[t] - v;
    if (b == NB - 1 && t == 0) rowptr[N_NODES] = N_EDGES;
}

// Stage B2: one block per bucket: final scatter within the bucket's own CSR
// window (~32 KB, single block -> single L2 -> full-line writebacks).
__global__ __launch_bounds__(256) void k_b2(const int* __restrict__ HOFF, const u64* __restrict__ tmp,
                                            const float* __restrict__ dis, const int* __restrict__ rowptr,
                                            int2* __restrict__ edges) {
    __shared__ int cur[256];
    __shared__ float disl[256];
    __shared__ int sbeg, send;
    int b = blockIdx.x, t = threadIdx.x;
    int lo = b << 8;
    int n = lo + t;
    cur[t] = (n < N_NODES) ? rowptr[n] : 0;
    disl[t] = (n < N_NODES) ? dis[n] : 0.0f;
    if (t == 0) {
        sbeg = HOFF[b * NC];
        send = (b + 1 < NB) ? HOFF[(b + 1) * NC] : N_EDGES;
    }
    __syncthreads();
    for (int e = sbeg + t; e < send; e += 256) {
        u64 r = tmp[e];
        int s = (int)(r & 0x1FFFF);
        int loc = (int)((r >> 17) & 0x1FFFF) - lo;
        float w = (float)(r >> 34) * (1.0f / 1073741824.0f);
        float coef = dis[s] * w * disl[loc];
        int pos = atomicAdd(&cur[loc], 1);
        edges[pos] = make_int2(s, __float_as_int(coef));
    }
}

// ---------------- W split (all 3 layers in one launch) ----------------
__global__ void k_wsplit3(const float* __restrict__ W1, const float* __restrict__ W2,
                          const float* __restrict__ W3, ushort* __restrict__ wsp) {
    int gid = blockIdx.x * 256 + threadIdx.x;   // 0..49151
    int l = gid >> 14;
    int i = gid & 16383;
    const float* W = (l == 0) ? W1 : (l == 1) ? W2 : W3;
    ushort* Wht = wsp + l * 32768;
    ushort* Wlt = Wht + 16384;
    int k = i >> 7, c = i & 127;
    float w = W[i];
    ushort wh = f2bf(w);
    ushort wl = f2bf(w - bf2f(wh));
    int j = k >> 3;
    int off = c * 128 + (((j ^ (c & 7)) << 3) | (k & 7));
    Wht[off] = wh;
    Wlt[off] = wl;
}

// ---------------- MFMA GEMM: h(bf16) = x(fp32) @ W, persistent-W grid-stride ----------------
__global__ __launch_bounds__(256) void k_gemm_mfma(
    const float* __restrict__ x, const ushort* __restrict__ Wht,
    const ushort* __restrict__ Wlt, ushort* __restrict__ hb)
{
    __shared__ ushort WH[16384];   // 32 KB
    __shared__ ushort WL[16384];   // 32 KB
    __shared__ ushort XH[4096];    // 8 KB
    __shared__ ushort XL[4096];    // 8 KB

    const int tx = threadIdx.x;

    // stage W once per block
    for (int i = tx; i < 2048; i += 256) {
        ((uint4*)WH)[i] = ((const uint4*)Wht)[i];
        ((uint4*)WL)[i] = ((const uint4*)Wlt)[i];
    }

    const int wv = tx >> 6;
    const int lane = tx & 63;
    const int lr = lane & 15;
    const int g = lane >> 4;
    const int c0 = wv * 32 + lr;
    const int c1 = c0 + 16;

    const int xr = (tx * 2) >> 4;       // x-split row for this thread
    const int xjb = (tx * 2) & 15;      // x-split chunk base

    for (int tile = blockIdx.x; tile < N_TILES; tile += GEMM_BLOCKS) {
        const int row0 = tile * TILE_ROWS;
        __syncthreads();   // previous tile's LDS reads done (covers W stage on iter 0)

        // split x tile into XH/XL (each thread: 2 chunks of 8 floats)
        {
            const float* xp = x + (size_t)(row0 + xr) * D;
#pragma unroll
            for (int c = 0; c < 2; ++c) {
                int j = xjb + c;
                float4 a0 = *(const float4*)(xp + j * 8);
                float4 a1 = *(const float4*)(xp + j * 8 + 4);
                float v[8] = {a0.x, a0.y, a0.z, a0.w, a1.x, a1.y, a1.z, a1.w};
                uint4 uh, ul;
                uint* ph = (uint*)&uh; uint* pl = (uint*)&ul;
#pragma unroll
                for (int e = 0; e < 4; ++e) {
                    ushort h0 = f2bf(v[2 * e]),     h1 = f2bf(v[2 * e + 1]);
                    ushort l0 = f2bf(v[2 * e] - bf2f(h0));
                    ushort l1 = f2bf(v[2 * e + 1] - bf2f(h1));
                    ph[e] = (uint)h0 | ((uint)h1 << 16);
                    pl[e] = (uint)l0 | ((uint)l1 << 16);
                }
                int off = xr * 16 + (j ^ (xr & 7));
                ((uint4*)XH)[off] = uh;
                ((uint4*)XL)[off] = ul;
            }
        }
        __syncthreads();

        f32x4 acc[2][2] = {};
#pragma unroll
        for (int ks = 0; ks < 4; ++ks) {
            int co = ((ks * 4 + g) ^ (lr & 7)) << 3;
            short8 ah0 = *(short8*)&XH[lr * 128 + co];
            short8 ah1 = *(short8*)&XH[(16 + lr) * 128 + co];
            short8 al0 = *(short8*)&XL[lr * 128 + co];
            short8 al1 = *(short8*)&XL[(16 + lr) * 128 + co];
            short8 bh0 = *(short8*)&WH[c0 * 128 + co];
            short8 bh1 = *(short8*)&WH[c1 * 128 + co];
            short8 bl0 = *(short8*)&WL[c0 * 128 + co];
            short8 bl1 = *(short8*)&WL[c1 * 128 + co];

            acc[0][0] = __builtin_amdgcn_mfma_f32_16x16x32_bf16(ah0, bh0, acc[0][0], 0, 0, 0);
            acc[0][1] = __builtin_amdgcn_mfma_f32_16x16x32_bf16(ah0, bh1, acc[0][1], 0, 0, 0);
            acc[1][0] = __builtin_amdgcn_mfma_f32_16x16x32_bf16(ah1, bh0, acc[1][0], 0, 0, 0);
            acc[1][1] = __builtin_amdgcn_mfma_f32_16x16x32_bf16(ah1, bh1, acc[1][1], 0, 0, 0);
            acc[0][0] = __builtin_amdgcn_mfma_f32_16x16x32_bf16(al0, bh0, acc[0][0], 0, 0, 0);
            acc[0][1] = __builtin_amdgcn_mfma_f32_16x16x32_bf16(al0, bh1, acc[0][1], 0, 0, 0);
            acc[1][0] = __builtin_amdgcn_mfma_f32_16x16x32_bf16(al1, bh0, acc[1][0], 0, 0, 0);
            acc[1][1] = __builtin_amdgcn_mfma_f32_16x16x32_bf16(al1, bh1, acc[1][1], 0, 0, 0);
            acc[0][0] = __builtin_amdgcn_mfma_f32_16x16x32_bf16(ah0, bl0, acc[0][0], 0, 0, 0);
            acc[0][1] = __builtin_amdgcn_mfma_f32_16x16x32_bf16(ah0, bl1, acc[0][1], 0, 0, 0);
            acc[1][0] = __builtin_amdgcn_mfma_f32_16x16x32_bf16(ah1, bl0, acc[1][0], 0, 0, 0);
            acc[1][1] = __builtin_amdgcn_mfma_f32_16x16x32_bf16(ah1, bl1, acc[1][1], 0, 0, 0);
        }

#pragma unroll
        for (int rt = 0; rt < 2; ++rt) {
#pragma unroll
            for (int ct = 0; ct < 2; ++ct) {
                int colb = wv * 32 + ct * 16 + lr;
#pragma unroll
                for (int e = 0; e < 4; ++e) {
                    int row = row0 + rt * 16 + g * 4 + e;
                    hb[(size_t)row * D + colb] = f2bf(acc[rt][ct][e]);
                }
            }
        }
    }
}

// ---------------- gather: out[n] = prelu( sum coef*h[src] + dis^2*h[n] + b ) ----------------
// one wave per node; 4 slots x 2-deep unroll = 8 edges in flight.
__global__ __launch_bounds__(256) void k_gather(
    const int* __restrict__ rowptr, const int2* __restrict__ edges,
    const ushort* __restrict__ hb, const float* __restrict__ dis,
    const float* __restrict__ b, const float* __restrict__ alpha,
    float* __restrict__ out)
{
    int gid = blockIdx.x * 256 + threadIdx.x;
    int n = gid >> 6;
    if (n >= N_NODES) return;
    int lane = gid & 63;
    int q = lane >> 4;           // edge slot 0..3
    int c0 = (lane & 15) * 8;    // 8 cols per lane

    int beg = rowptr[n], end = rowptr[n + 1];
    float acc[8] = {0.f, 0.f, 0.f, 0.f, 0.f, 0.f, 0.f, 0.f};

    int e = beg + q;
    for (; e + 4 < end; e += 8) {
        int2 sc0 = edges[e];
        int2 sc1 = edges[e + 4];
        uint4 hv0 = *(const uint4*)&hb[(size_t)sc0.x * D + c0];
        uint4 hv1 = *(const uint4*)&hb[(size_t)sc1.x * D + c0];
        float ca = __int_as_float(sc0.y);
        float cb = __int_as_float(sc1.y);
#pragma unroll
        for (int j = 0; j < 4; ++j) {
            uint w0 = ((const uint*)&hv0)[j];
            uint w1 = ((const uint*)&hv1)[j];
            acc[2 * j]     = fmaf(ca, __uint_as_float(w0 << 16),         acc[2 * j]);
            acc[2 * j + 1] = fmaf(ca, __uint_as_float(w0 & 0xffff0000u), acc[2 * j + 1]);
            acc[2 * j]     = fmaf(cb, __uint_as_float(w1 << 16),         acc[2 * j]);
            acc[2 * j + 1] = fmaf(cb, __uint_as_float(w1 & 0xffff0000u), acc[2 * j + 1]);
        }
    }
    if (e < end) {
        int2 sc = edges[e];
        float c = __int_as_float(sc.y);
        uint4 hv = *(const uint4*)&hb[(size_t)sc.x * D + c0];
#pragma unroll
        for (int j = 0; j < 4; ++j) {
            uint w = ((const uint*)&hv)[j];
            acc[2 * j]     = fmaf(c, __uint_as_float(w << 16),         acc[2 * j]);
            acc[2 * j + 1] = fmaf(c, __uint_as_float(w & 0xffff0000u), acc[2 * j + 1]);
        }
    }

#pragma unroll
    for (int j = 0; j < 8; ++j) {
        acc[j] += __shfl_xor(acc[j], 16);
        acc[j] += __shfl_xor(acc[j], 32);
    }

    if (q == 0) {
        float di = dis[n];
        float d2 = di * di;
        uint4 hv = *(const uint4*)&hb[(size_t)n * D + c0];
        float r[8];
#pragma unroll
        for (int j = 0; j < 4; ++j) {
            uint w = ((const uint*)&hv)[j];
            float lo = __uint_as_float(w << 16);
            float hi = __uint_as_float(w & 0xffff0000u);
            r[2 * j]     = acc[2 * j]     + d2 * lo + b[c0 + 2 * j];
            r[2 * j + 1] = acc[2 * j + 1] + d2 * hi + b[c0 + 2 * j + 1];
        }
#pragma unroll
        for (int j = 0; j < 8; ++j) {
            float av = alpha[c0 + j];
            r[j] = r[j] >= 0.f ? r[j] : av * r[j];
        }
        *(float4*)&out[(size_t)n * D + c0]     = make_float4(r[0], r[1], r[2], r[3]);
        *(float4*)&out[(size_t)n * D + c0 + 4] = make_float4(r[4], r[5], r[6], r[7]);
    }
}

// ---------------- launch ----------------

extern "C" void kernel_launch(void* const* d_in, const int* in_sizes, int n_in,
                              void* d_out, int out_size, void* d_ws, size_t ws_size,
                              hipStream_t stream) {
    const float* x   = (const float*)d_in[0];
    const int*   ei  = (const int*)d_in[1];
    const float* ew  = (const float*)d_in[2];
    const float* W1  = (const float*)d_in[3];
    const float* b1  = (const float*)d_in[4];
    const float* a1  = (const float*)d_in[5];
    const float* W2  = (const float*)d_in[6];
    const float* b2  = (const float*)d_in[7];
    const float* a2  = (const float*)d_in[8];
    const float* W3  = (const float*)d_in[9];
    const float* b3  = (const float*)d_in[10];
    const float* a3  = (const float*)d_in[11];

    const int* src = ei;
    const int* dst = ei + N_EDGES;

    float* out = (float*)d_out;

    // workspace layout (8-byte alignment maintained; ~53.5 MB total)
    ushort* hb    = (ushort*)d_ws;                       // N*D bf16   (25.6 MB)
    int2*   edges = (int2*)(hb + (size_t)N_NODES * D);   // E int2     (12.8 MB)
    u64*    tmp   = (u64*)(edges + N_EDGES);             // E u64      (12.8 MB)
    int*    H     = (int*)(tmp + N_EDGES);               // HLEN       (0.61 MB)
    int*    HOFF  = H + HLEN;                            // HLEN       (0.61 MB)
    int*    bsum  = HOFF + HLEN;                         // 256
    float*  dis   = (float*)(bsum + 256);                // N
    int*    rowptr= (int*)(dis + N_NODES);               // N+1 (+pad to even)
    ushort* wsp   = (ushort*)(rowptr + N_NODES + 2);     // 6 x 16384 ushorts
    ushort* Wht1 = wsp;             ushort* Wlt1 = wsp + 16384;
    ushort* Wht2 = wsp + 32768;     ushort* Wlt2 = wsp + 32768 + 16384;
    ushort* Wht3 = wsp + 65536;     ushort* Wlt3 = wsp + 65536 + 16384;

    // W splits (independent of everything else), one launch
    k_wsplit3<<<192, 256, 0, stream>>>(W1, W2, W3, wsp);

    // CSR build: hist -> scan -> bucket scatter -> per-bucket b1 -> b2
    k_hist<<<NC, 256, 0, stream>>>(dst, H);
    k_scanA<<<SCAN_BLK, 256, 0, stream>>>(H, HOFF, bsum);
    k_scanB<<<1, 256, 0, stream>>>(bsum);
    k_scanC<<<(HLEN + 255) / 256, 256, 0, stream>>>(HOFF, bsum);
    k_pscat<<<NC, 256, 0, stream>>>(src, dst, ew, HOFF, tmp);
    k_b1<<<NB, 256, 0, stream>>>(HOFF, tmp, dis, rowptr);
    k_b2<<<NB, 256, 0, stream>>>(HOFF, tmp, dis, rowptr, edges);

    const int gather_blocks = (N_NODES * 64) / 256;  // 25000

    // ----- layer 1 -----
    k_gemm_mfma<<<GEMM_BLOCKS, 256, 0, stream>>>(x, Wht1, Wlt1, hb);
    k_gather<<<gather_blocks, 256, 0, stream>>>(rowptr, edges, hb, dis, b1, a1, out);
    // ----- layer 2 -----
    k_gemm_mfma<<<GEMM_BLOCKS, 256, 0, stream>>>(out, Wht2, Wlt2, hb);
    k_gather<<<gather_blocks, 256, 0, stream>>>(rowptr, edges, hb, dis, b2, a2, out);
    // ----- layer 3 -----
    k_gemm_mfma<<<GEMM_BLOCKS, 256, 0, stream>>>(out, Wht3, Wlt3, hb);
    k_gather<<<gather_blocks, 256, 0, stream>>>(rowptr, edges, hb, dis, b3, a3, out);
}

// Round 10
// 378.852 us; speedup vs baseline: 11.2050x; 1.0145x over previous
//
#include <hip/hip_runtime.h>

#define N_NODES 100000
#define N_EDGES 1600000
#define D 128
#define TILE_ROWS 32
#define N_TILES (N_NODES / TILE_ROWS)        // 3125
#define GEMM_BLOCKS 512
#define CHUNK 4096
#define NC ((N_EDGES + CHUNK - 1) / CHUNK)   // 391 chunks
#define NB ((N_NODES + 255) / 256)           // 391 buckets (256 nodes each)
#define HLEN (NB * NC)                       // 152881
#define SCAN_BLK ((HLEN + 1023) / 1024)      // 150
#define SB_SHIFT 13
#define NSB 13                               // ceil(100000 / 8192)
#define SBP 17                               // padded stride (bank spread)
#define EBUF 5120                            // LDS staging (u64); mean bucket = 4096

typedef unsigned int uint;
typedef unsigned long long u64;
typedef short short8 __attribute__((ext_vector_type(8)));
typedef float f32x4 __attribute__((ext_vector_type(4)));

__device__ inline ushort f2bf(float f) {  // RTNE bf16 (finite inputs)
    union { float f; uint u; } v; v.f = f;
    uint r = v.u + 0x7fffu + ((v.u >> 16) & 1u);
    return (ushort)(r >> 16);
}
__device__ inline float bf2f(ushort b) {
    union { uint u; float f; } v; v.u = ((uint)b) << 16;
    return v.f;
}

// ================= CSR build: two-level bucket sort, no global atomics =================

// Stage 1: per-chunk histogram over dst>>8. H is chunk-major: H[c*NB + b].
__global__ __launch_bounds__(256) void k_hist(const int* __restrict__ dst, int* __restrict__ H) {
    __shared__ int hist[NB];
    int c = blockIdx.x;
    for (int i = threadIdx.x; i < NB; i += 256) hist[i] = 0;
    __syncthreads();
    int base = c * CHUNK;
    int lim = N_EDGES - base; if (lim > CHUNK) lim = CHUNK;
    for (int k = threadIdx.x; k < lim; k += 256)
        atomicAdd(&hist[dst[base + k] >> 8], 1);
    __syncthreads();
    for (int i = threadIdx.x; i < NB; i += 256) H[c * NB + i] = hist[i];
}

// Stage 2: exclusive scan of H in bucket-major logical order l = b*NC + c.
__global__ __launch_bounds__(256) void k_scanA(const int* __restrict__ H, int* __restrict__ HOFF,
                                               int* __restrict__ bsum) {
    __shared__ int sd[256];
    int t = threadIdx.x;
    int base = blockIdx.x * 1024 + t * 4;
    int v[4];
#pragma unroll
    for (int j = 0; j < 4; ++j) {
        int l = base + j;
        v[j] = (l < HLEN) ? H[(l % NC) * NB + (l / NC)] : 0;   // transposed read
    }
    int lsum = v[0] + v[1] + v[2] + v[3];
    sd[t] = lsum;
    __syncthreads();
    for (int off = 1; off < 256; off <<= 1) {
        int x = (t >= off) ? sd[t - off] : 0;
        __syncthreads();
        sd[t] += x;
        __syncthreads();
    }
    int excl = sd[t] - lsum;
    if (base + 0 < HLEN) HOFF[base + 0] = excl;
    if (base + 1 < HLEN) HOFF[base + 1] = excl + v[0];
    if (base + 2 < HLEN) HOFF[base + 2] = excl + v[0] + v[1];
    if (base + 3 < HLEN) HOFF[base + 3] = excl + v[0] + v[1] + v[2];
    if (t == 255) bsum[blockIdx.x] = sd[255];
}

// parallel scan of the 150 block sums
__global__ __launch_bounds__(256) void k_scanB(int* __restrict__ bsum) {
    __shared__ int sd[256];
    int t = threadIdx.x;
    int v = (t < SCAN_BLK) ? bsum[t] : 0;
    sd[t] = v;
    __syncthreads();
    for (int off = 1; off < 256; off <<= 1) {
        int x = (t >= off) ? sd[t - off] : 0;
        __syncthreads();
        sd[t] += x;
        __syncthreads();
    }
    if (t < SCAN_BLK) bsum[t] = sd[t] - v;
}

__global__ void k_scanC(int* __restrict__ HOFF, const int* __restrict__ bsum) {
    int i = blockIdx.x * blockDim.x + threadIdx.x;
    if (i < HLEN) HOFF[i] += bsum[i >> 10];
}

// Stage 3: scatter u64 records (src | dst<<17 | Q30(ew)<<34) into bucket-major tmp.
__global__ __launch_bounds__(256) void k_pscat(const int* __restrict__ src, const int* __restrict__ dst,
                                               const float* __restrict__ ew, const int* __restrict__ HOFF,
                                               u64* __restrict__ tmp) {
    __shared__ int cur[NB];
    int c = blockIdx.x;
    for (int i = threadIdx.x; i < NB; i += 256) cur[i] = HOFF[i * NC + c];
    __syncthreads();
    int base = c * CHUNK;
    int lim = N_EDGES - base; if (lim > CHUNK) lim = CHUNK;
    for (int k = threadIdx.x; k < lim; k += 256) {
        int e = base + k;
        int s = src[e], t = dst[e];
        u64 q = (u64)llrintf(ew[e] * 1073741824.0f);   // Q30, ew in [0,1)
        int pos = atomicAdd(&cur[t >> 8], 1);
        tmp[pos] = (u64)s | ((u64)t << 17) | (q << 34);
    }
}

// Fused bucket kernel: one block per 256-node bucket.
// pass 1: stage slice in LDS + per-(node, src-block) counts + weighted degree.
// -> dis, rowptr, per-(node,sb) offsets.
// pass 2: scatter final records sorted by (node, src-block).
// Edge record stores cf = w * dis[dst] ONLY (dis[src] is folded into hb by the
// GEMM epilogue) -> no cross-bucket dependency -> single kernel is race-free.
__global__ __launch_bounds__(256) void k_bfused(const int* __restrict__ HOFF, const u64* __restrict__ tmp,
                                                float* __restrict__ dis, int* __restrict__ rowptr,
                                                int2* __restrict__ edges) {
    __shared__ u64 ebuf[EBUF];        // 40 KB
    __shared__ u64 degq[256];         // 2 KB
    __shared__ int cnt2[256][SBP];    // 17 KB (counts -> offsets -> cursors)
    __shared__ int sd[256];           // 1 KB
    __shared__ float disl[256];       // 1 KB
    int b = blockIdx.x, t = threadIdx.x;
    int beg = HOFF[b * NC];
    int end = (b + 1 < NB) ? HOFF[(b + 1) * NC] : N_EDGES;
    int total = end - beg;
    bool fit = (total <= EBUF);
    degq[t] = 0;
#pragma unroll
    for (int j = 0; j < SBP; ++j) cnt2[t][j] = 0;
    __syncthreads();
    int lo = b << 8;

    // pass 1
    for (int e = beg + t; e < end; e += 256) {
        u64 r = tmp[e];
        if (fit) ebuf[e - beg] = r;
        int loc = (int)((r >> 17) & 0x1FFFF) - lo;
        int sb = (int)(r & 0x1FFFF) >> SB_SHIFT;
        atomicAdd(&cnt2[loc][sb], 1);
        atomicAdd(&degq[loc], r >> 34);
    }
    __syncthreads();

    // dis + node totals
    int n = lo + t;
    float dv = 0.0f;
    if (n < N_NODES) {
        float deg = (float)((double)degq[t] * (1.0 / 1073741824.0));
        dv = rsqrtf(deg + 1.0f);   // self-loop weight 1
        dis[n] = dv;
    }
    disl[t] = dv;
    int tot = 0;
#pragma unroll
    for (int j = 0; j < NSB; ++j) tot += cnt2[t][j];
    sd[t] = tot;
    __syncthreads();
    for (int off = 1; off < 256; off <<= 1) {
        int x = (t >= off) ? sd[t - off] : 0;
        __syncthreads();
        sd[t] += x;
        __syncthreads();
    }
    int nbase = beg + sd[t] - tot;
    if (n < N_NODES) rowptr[n] = nbase;
    if (b == NB - 1 && t == 0) rowptr[N_NODES] = N_EDGES;
    // per-(node, sb) exclusive offsets (cnt2 becomes cursor array)
    {
        int run = nbase;
#pragma unroll
        for (int j = 0; j < NSB; ++j) { int c = cnt2[t][j]; cnt2[t][j] = run; run += c; }
    }
    __syncthreads();

    // pass 2: scatter sorted by (node, src-block)
    if (fit) {
        for (int i = t; i < total; i += 256) {
            u64 r = ebuf[i];
            int s = (int)(r & 0x1FFFF);
            int loc = (int)((r >> 17) & 0x1FFFF) - lo;
            float w = (float)(r >> 34) * (1.0f / 1073741824.0f);
            float cf = w * disl[loc];
            int pos = atomicAdd(&cnt2[loc][s >> SB_SHIFT], 1);
            edges[pos] = make_int2(s, __float_as_int(cf));
        }
    } else {
        for (int e = beg + t; e < end; e += 256) {
            u64 r = tmp[e];
            int s = (int)(r & 0x1FFFF);
            int loc = (int)((r >> 17) & 0x1FFFF) - lo;
            float w = (float)(r >> 34) * (1.0f / 1073741824.0f);
            float cf = w * disl[loc];
            int pos = atomicAdd(&cnt2[loc][s >> SB_SHIFT], 1);
            edges[pos] = make_int2(s, __float_as_int(cf));
        }
    }
}

// ---------------- W split (all 3 layers in one launch) ----------------
__global__ void k_wsplit3(const float* __restrict__ W1, const float* __restrict__ W2,
                          const float* __restrict__ W3, ushort* __restrict__ wsp) {
    int gid = blockIdx.x * 256 + threadIdx.x;   // 0..49151
    int l = gid >> 14;
    int i = gid & 16383;
    const float* W = (l == 0) ? W1 : (l == 1) ? W2 : W3;
    ushort* Wht = wsp + l * 32768;
    ushort* Wlt = Wht + 16384;
    int k = i >> 7, c = i & 127;
    float w = W[i];
    ushort wh = f2bf(w);
    ushort wl = f2bf(w - bf2f(wh));
    int j = k >> 3;
    int off = c * 128 + (((j ^ (c & 7)) << 3) | (k & 7));
    Wht[off] = wh;
    Wlt[off] = wl;
}

// ---------------- MFMA GEMM: hb = bf16( dis[row] * (x @ W) ), persistent-W ----------------
__global__ __launch_bounds__(256) void k_gemm_mfma(
    const float* __restrict__ x, const ushort* __restrict__ Wht,
    const ushort* __restrict__ Wlt, const float* __restrict__ dis,
    ushort* __restrict__ hb)
{
    __shared__ ushort WH[16384];   // 32 KB
    __shared__ ushort WL[16384];   // 32 KB
    __shared__ ushort XH[4096];    // 8 KB
    __shared__ ushort XL[4096];    // 8 KB

    const int tx = threadIdx.x;

    // stage W once per block
    for (int i = tx; i < 2048; i += 256) {
        ((uint4*)WH)[i] = ((const uint4*)Wht)[i];
        ((uint4*)WL)[i] = ((const uint4*)Wlt)[i];
    }

    const int wv = tx >> 6;
    const int lane = tx & 63;
    const int lr = lane & 15;
    const int g = lane >> 4;
    const int c0 = wv * 32 + lr;
    const int c1 = c0 + 16;

    const int xr = (tx * 2) >> 4;       // x-split row for this thread
    const int xjb = (tx * 2) & 15;      // x-split chunk base

    for (int tile = blockIdx.x; tile < N_TILES; tile += GEMM_BLOCKS) {
        const int row0 = tile * TILE_ROWS;
        __syncthreads();   // previous tile's LDS reads done (covers W stage on iter 0)

        // split x tile into XH/XL (each thread: 2 chunks of 8 floats)
        {
            const float* xp = x + (size_t)(row0 + xr) * D;
#pragma unroll
            for (int c = 0; c < 2; ++c) {
                int j = xjb + c;
                float4 a0 = *(const float4*)(xp + j * 8);
                float4 a1 = *(const float4*)(xp + j * 8 + 4);
                float v[8] = {a0.x, a0.y, a0.z, a0.w, a1.x, a1.y, a1.z, a1.w};
                uint4 uh, ul;
                uint* ph = (uint*)&uh; uint* pl = (uint*)&ul;
#pragma unroll
                for (int e = 0; e < 4; ++e) {
                    ushort h0 = f2bf(v[2 * e]),     h1 = f2bf(v[2 * e + 1]);
                    ushort l0 = f2bf(v[2 * e] - bf2f(h0));
                    ushort l1 = f2bf(v[2 * e + 1] - bf2f(h1));
                    ph[e] = (uint)h0 | ((uint)h1 << 16);
                    pl[e] = (uint)l0 | ((uint)l1 << 16);
                }
                int off = xr * 16 + (j ^ (xr & 7));
                ((uint4*)XH)[off] = uh;
                ((uint4*)XL)[off] = ul;
            }
        }
        __syncthreads();

        f32x4 acc[2][2] = {};
#pragma unroll
        for (int ks = 0; ks < 4; ++ks) {
            int co = ((ks * 4 + g) ^ (lr & 7)) << 3;
            short8 ah0 = *(short8*)&XH[lr * 128 + co];
            short8 ah1 = *(short8*)&XH[(16 + lr) * 128 + co];
            short8 al0 = *(short8*)&XL[lr * 128 + co];
            short8 al1 = *(short8*)&XL[(16 + lr) * 128 + co];
            short8 bh0 = *(short8*)&WH[c0 * 128 + co];
            short8 bh1 = *(short8*)&WH[c1 * 128 + co];
            short8 bl0 = *(short8*)&WL[c0 * 128 + co];
            short8 bl1 = *(short8*)&WL[c1 * 128 + co];

            acc[0][0] = __builtin_amdgcn_mfma_f32_16x16x32_bf16(ah0, bh0, acc[0][0], 0, 0, 0);
            acc[0][1] = __builtin_amdgcn_mfma_f32_16x16x32_bf16(ah0, bh1, acc[0][1], 0, 0, 0);
            acc[1][0] = __builtin_amdgcn_mfma_f32_16x16x32_bf16(ah1, bh0, acc[1][0], 0, 0, 0);
            acc[1][1] = __builtin_amdgcn_mfma_f32_16x16x32_bf16(ah1, bh1, acc[1][1], 0, 0, 0);
            acc[0][0] = __builtin_amdgcn_mfma_f32_16x16x32_bf16(al0, bh0, acc[0][0], 0, 0, 0);
            acc[0][1] = __builtin_amdgcn_mfma_f32_16x16x32_bf16(al0, bh1, acc[0][1], 0, 0, 0);
            acc[1][0] = __builtin_amdgcn_mfma_f32_16x16x32_bf16(al1, bh0, acc[1][0], 0, 0, 0);
            acc[1][1] = __builtin_amdgcn_mfma_f32_16x16x32_bf16(al1, bh1, acc[1][1], 0, 0, 0);
            acc[0][0] = __builtin_amdgcn_mfma_f32_16x16x32_bf16(ah0, bl0, acc[0][0], 0, 0, 0);
            acc[0][1] = __builtin_amdgcn_mfma_f32_16x16x32_bf16(ah0, bl1, acc[0][1], 0, 0, 0);
            acc[1][0] = __builtin_amdgcn_mfma_f32_16x16x32_bf16(ah1, bl0, acc[1][0], 0, 0, 0);
            acc[1][1] = __builtin_amdgcn_mfma_f32_16x16x32_bf16(ah1, bl1, acc[1][1], 0, 0, 0);
        }

#pragma unroll
        for (int rt = 0; rt < 2; ++rt) {
            float4 dvq = *(const float4*)&dis[row0 + rt * 16 + g * 4];
            const float dvv[4] = {dvq.x, dvq.y, dvq.z, dvq.w};
#pragma unroll
            for (int ct = 0; ct < 2; ++ct) {
                int colb = wv * 32 + ct * 16 + lr;
#pragma unroll
                for (int e = 0; e < 4; ++e) {
                    int row = row0 + rt * 16 + g * 4 + e;
                    hb[(size_t)row * D + colb] = f2bf(dvv[e] * acc[rt][ct][e]);
                }
            }
        }
    }
}

// ---------------- gather: out[n] = prelu( sum cf*hb'[src] + dis[n]*hb'[n] + b ) ----------------
// hb' = dis*h ; cf = w*dis[dst]. one wave per node; 4 slots x 2-deep unroll.
__global__ __launch_bounds__(256) void k_gather(
    const int* __restrict__ rowptr, const int2* __restrict__ edges,
    const ushort* __restrict__ hb, const float* __restrict__ dis,
    const float* __restrict__ b, const float* __restrict__ alpha,
    float* __restrict__ out)
{
    int gid = blockIdx.x * 256 + threadIdx.x;
    int n = gid >> 6;
    if (n >= N_NODES) return;
    int lane = gid & 63;
    int q = lane >> 4;           // edge slot 0..3
    int c0 = (lane & 15) * 8;    // 8 cols per lane

    int beg = rowptr[n], end = rowptr[n + 1];
    float acc[8] = {0.f, 0.f, 0.f, 0.f, 0.f, 0.f, 0.f, 0.f};

    int e = beg + q;
    for (; e + 4 < end; e += 8) {
        int2 sc0 = edges[e];
        int2 sc1 = edges[e + 4];
        uint4 hv0 = *(const uint4*)&hb[(size_t)sc0.x * D + c0];
        uint4 hv1 = *(const uint4*)&hb[(size_t)sc1.x * D + c0];
        float ca = __int_as_float(sc0.y);
        float cb = __int_as_float(sc1.y);
#pragma unroll
        for (int j = 0; j < 4; ++j) {
            uint w0 = ((const uint*)&hv0)[j];
            uint w1 = ((const uint*)&hv1)[j];
            acc[2 * j]     = fmaf(ca, __uint_as_float(w0 << 16),         acc[2 * j]);
            acc[2 * j + 1] = fmaf(ca, __uint_as_float(w0 & 0xffff0000u), acc[2 * j + 1]);
            acc[2 * j]     = fmaf(cb, __uint_as_float(w1 << 16),         acc[2 * j]);
            acc[2 * j + 1] = fmaf(cb, __uint_as_float(w1 & 0xffff0000u), acc[2 * j + 1]);
        }
    }
    if (e < end) {
        int2 sc = edges[e];
        float c = __int_as_float(sc.y);
        uint4 hv = *(const uint4*)&hb[(size_t)sc.x * D + c0];
#pragma unroll
        for (int j = 0; j < 4; ++j) {
            uint w = ((const uint*)&hv)[j];
            acc[2 * j]     = fmaf(c, __uint_as_float(w << 16),         acc[2 * j]);
            acc[2 * j + 1] = fmaf(c, __uint_as_float(w & 0xffff0000u), acc[2 * j + 1]);
        }
    }

#pragma unroll
    for (int j = 0; j < 8; ++j) {
        acc[j] += __shfl_xor(acc[j], 16);
        acc[j] += __shfl_xor(acc[j], 32);
    }

    if (q == 0) {
        float di = dis[n];
        uint4 hv = *(const uint4*)&hb[(size_t)n * D + c0];
        float r[8];
#pragma unroll
        for (int j = 0; j < 4; ++j) {
            uint w = ((const uint*)&hv)[j];
            float lo = __uint_as_float(w << 16);
            float hi = __uint_as_float(w & 0xffff0000u);
            r[2 * j]     = acc[2 * j]     + di * lo + b[c0 + 2 * j];
            r[2 * j + 1] = acc[2 * j + 1] + di * hi + b[c0 + 2 * j + 1];
        }
#pragma unroll
        for (int j = 0; j < 8; ++j) {
            float av = alpha[c0 + j];
            r[j] = r[j] >= 0.f ? r[j] : av * r[j];
        }
        *(float4*)&out[(size_t)n * D + c0]     = make_float4(r[0], r[1], r[2], r[3]);
        *(float4*)&out[(size_t)n * D + c0 + 4] = make_float4(r[4], r[5], r[6], r[7]);
    }
}

// ---------------- launch ----------------

extern "C" void kernel_launch(void* const* d_in, const int* in_sizes, int n_in,
                              void* d_out, int out_size, void* d_ws, size_t ws_size,
                              hipStream_t stream) {
    const float* x   = (const float*)d_in[0];
    const int*   ei  = (const int*)d_in[1];
    const float* ew  = (const float*)d_in[2];
    const float* W1  = (const float*)d_in[3];
    const float* b1  = (const float*)d_in[4];
    const float* a1  = (const float*)d_in[5];
    const float* W2  = (const float*)d_in[6];
    const float* b2  = (const float*)d_in[7];
    const float* a2  = (const float*)d_in[8];
    const float* W3  = (const float*)d_in[9];
    const float* b3  = (const float*)d_in[10];
    const float* a3  = (const float*)d_in[11];

    const int* src = ei;
    const int* dst = ei + N_EDGES;

    float* out = (float*)d_out;

    // workspace layout, explicit byte offsets, every region 16B-aligned (~53.4 MB)
    char* base = (char*)d_ws;
    ushort* hb    = (ushort*)(base);               // 25,600,000 B
    int2*   edges = (int2*)(base + 25600000);      // 12,800,000 B
    u64*    tmp   = (u64*)(base + 38400000);       // 12,800,000 B
    float*  dis   = (float*)(base + 51200000);     //    400,000 B
    int*    H     = (int*)(base + 51600000);       //    611,536 B (HLEN padded)
    int*    HOFF  = (int*)(base + 52211536);       //    611,536 B
    int*    bsum  = (int*)(base + 52823072);       //      1,024 B
    int*    rowptr= (int*)(base + 52824096);       //    400,016 B
    ushort* wsp   = (ushort*)(base + 53224112);    //    196,608 B
    ushort* Wht1 = wsp;             ushort* Wlt1 = wsp + 16384;
    ushort* Wht2 = wsp + 32768;     ushort* Wlt2 = wsp + 32768 + 16384;
    ushort* Wht3 = wsp + 65536;     ushort* Wlt3 = wsp + 65536 + 16384;

    // W splits (independent of everything else), one launch
    k_wsplit3<<<192, 256, 0, stream>>>(W1, W2, W3, wsp);

    // CSR build: hist -> scan -> bucket scatter -> fused per-bucket build
    k_hist<<<NC, 256, 0, stream>>>(dst, H);
    k_scanA<<<SCAN_BLK, 256, 0, stream>>>(H, HOFF, bsum);
    k_scanB<<<1, 256, 0, stream>>>(bsum);
    k_scanC<<<(HLEN + 255) / 256, 256, 0, stream>>>(HOFF, bsum);
    k_pscat<<<NC, 256, 0, stream>>>(src, dst, ew, HOFF, tmp);
    k_bfused<<<NB, 256, 0, stream>>>(HOFF, tmp, dis, rowptr, edges);

    const int gather_blocks = (N_NODES * 64) / 256;  // 25000

    // ----- layer 1 -----
    k_gemm_mfma<<<GEMM_BLOCKS, 256, 0, stream>>>(x, Wht1, Wlt1, dis, hb);
    k_gather<<<gather_blocks, 256, 0, stream>>>(rowptr, edges, hb, dis, b1, a1, out);
    // ----- layer 2 -----
    k_gemm_mfma<<<GEMM_BLOCKS, 256, 0, stream>>>(out, Wht2, Wlt2, dis, hb);
    k_gather<<<gather_blocks, 256, 0, stream>>>(rowptr, edges, hb, dis, b2, a2, out);
    // ----- layer 3 -----
    k_gemm_mfma<<<GEMM_BLOCKS, 256, 0, stream>>>(out, Wht3, Wlt3, dis, hb);
    k_gather<<<gather_blocks, 256, 0, stream>>>(rowptr, edges, hb, dis, b3, a3, out);
}